// Round 2
// baseline (1855.944 us; speedup 1.0000x reference)
//
#include <hip/hip_runtime.h>
#include <math.h>

#define SEQ     2048
#define HID     2048
#define NH      32
#define NKV     8
#define HD      64
#define QCOLS   (NH*HD)          // 2048
#define KVCOLS  (NKV*HD)         // 512
#define NTOT    (QCOLS + 2*KVCOLS)

#define BM 64
#define BN 64
#define BK 16
#define LDT 68   // padded LDS row stride (floats), float4-aligned

// ---------------------------------------------------------------------------
// K0: RoPE cos/sin tables. angle(s,d) = s * theta^(-(d&31)/32)
// ---------------------------------------------------------------------------
__global__ void rope_table_kernel(float* __restrict__ cosT, float* __restrict__ sinT) {
    int i = blockIdx.x * blockDim.x + threadIdx.x;   // 0 .. SEQ*HD-1
    int srow = i >> 6;
    int d = i & 63;
    float inv = powf(500000.0f, -(float)(d & 31) / 32.0f);
    float a = (float)srow * inv;
    cosT[i] = cosf(a);
    sinT[i] = sinf(a);
}

// ---------------------------------------------------------------------------
// K1: fused QKV projection GEMM with RoPE epilogue on Q and K columns.
// X[SEQ][HID] @ [Wq | Wk | Wv] -> Q[SEQ][2048], K[SEQ][512], V[SEQ][512]
// ---------------------------------------------------------------------------
__global__ __launch_bounds__(256) void qkv_kernel(
    const float* __restrict__ X,  const float* __restrict__ Wq,
    const float* __restrict__ Wk, const float* __restrict__ Wv,
    const float* __restrict__ cosT, const float* __restrict__ sinT,
    float* __restrict__ Q, float* __restrict__ K, float* __restrict__ V)
{
    __shared__ float As[BK][LDT];   // transposed A tile: As[k][m]
    __shared__ float Bs[BK][LDT];
    int n0 = blockIdx.x * BN;       // 0..3008
    int m0 = blockIdx.y * BM;
    const float* B; int ldb; int bcol0; int region; // 0=Q 1=K 2=V
    if (n0 < QCOLS)              { B = Wq; ldb = QCOLS;  bcol0 = n0;                 region = 0; }
    else if (n0 < QCOLS+KVCOLS)  { B = Wk; ldb = KVCOLS; bcol0 = n0 - QCOLS;         region = 1; }
    else                         { B = Wv; ldb = KVCOLS; bcol0 = n0 - QCOLS - KVCOLS; region = 2; }

    int t = threadIdx.x;
    int tr = t >> 4, tc = t & 15;
    int arow = t >> 2;            // 0..63
    int acol = (t & 3) * 4;       // 0..12
    int brow = t >> 4;            // 0..15
    int bcol = (t & 15) * 4;      // 0..60

    float acc[4][4] = {};
    for (int k0 = 0; k0 < HID; k0 += BK) {
        float4 a4 = *(const float4*)&X[(size_t)(m0 + arow) * HID + k0 + acol];
        float4 b4 = *(const float4*)&B[(size_t)(k0 + brow) * ldb + bcol0 + bcol];
        As[acol+0][arow] = a4.x;
        As[acol+1][arow] = a4.y;
        As[acol+2][arow] = a4.z;
        As[acol+3][arow] = a4.w;
        *(float4*)&Bs[brow][bcol] = b4;
        __syncthreads();
        #pragma unroll
        for (int kk = 0; kk < BK; ++kk) {
            float4 av = *(const float4*)&As[kk][tr*4];
            float4 bv = *(const float4*)&Bs[kk][tc*4];
            float a[4] = {av.x, av.y, av.z, av.w};
            float b[4] = {bv.x, bv.y, bv.z, bv.w};
            #pragma unroll
            for (int i = 0; i < 4; ++i)
                #pragma unroll
                for (int j = 0; j < 4; ++j)
                    acc[i][j] += a[i] * b[j];
        }
        __syncthreads();
    }

    int nbase = n0 + tc * 4;          // global col of j=0
    int d0 = nbase & 63;              // dim within head (heads 64-aligned)
    #pragma unroll
    for (int i = 0; i < 4; ++i) {
        int srow = m0 + tr * 4 + i;
        float o[4] = {acc[i][0], acc[i][1], acc[i][2], acc[i][3]};
        if (region != 2) {
            // RoPE: out[2i]   = x[2i]*cos[2i]   - x[2i+1]*sin[2i]
            //       out[2i+1] = x[2i+1]*cos[2i+1] + x[2i]*sin[2i+1]
            #pragma unroll
            for (int p = 0; p < 2; ++p) {
                float x1 = o[2*p], x2 = o[2*p+1];
                int d = d0 + 2*p;
                float c0 = cosT[srow*HD + d],   s0 = sinT[srow*HD + d];
                float c1 = cosT[srow*HD + d+1], s1 = sinT[srow*HD + d+1];
                o[2*p]   = x1 * c0 - x2 * s0;
                o[2*p+1] = x2 * c1 + x1 * s1;
            }
        }
        float4 ov = make_float4(o[0], o[1], o[2], o[3]);
        if (region == 0)      *(float4*)&Q[(size_t)srow*QCOLS  + nbase] = ov;
        else if (region == 1) *(float4*)&K[(size_t)srow*KVCOLS + (nbase - QCOLS)] = ov;
        else                  *(float4*)&V[(size_t)srow*KVCOLS + (nbase - QCOLS - KVCOLS)] = ov;
    }
}

// ---------------------------------------------------------------------------
// K2: causal flash attention. One block per (q-tile of 64 rows, head).
// thread t: q-row r = t>>2, group g = t&3 owns k-cols / d-dims g*16..g*16+15
// ---------------------------------------------------------------------------
__global__ __launch_bounds__(256) void attn_kernel(
    const float* __restrict__ Q, const float* __restrict__ K,
    const float* __restrict__ V, float* __restrict__ O)
{
    __shared__ float Qs[64][LDT];
    __shared__ float Ks[64][LDT];
    __shared__ float Vs[64][LDT];
    __shared__ float Ps[64][LDT];
    int qt = blockIdx.x;
    int h  = blockIdx.y;
    int q0 = qt * 64;
    int kvh = h >> 2;               // 32 heads -> 8 kv heads (groups=4)
    int t = threadIdx.x;
    int r = t >> 2;
    int g = t & 3;

    #pragma unroll
    for (int i = 0; i < 4; ++i) {
        int f = i * 256 + t;        // float4 index 0..1023
        int row = f >> 4, col = (f & 15) * 4;
        *(float4*)&Qs[row][col] = *(const float4*)&Q[(size_t)(q0 + row) * QCOLS + h * HD + col];
    }

    float m = -1e30f, l = 0.0f;
    float o[16] = {};
    const float scale = 0.125f;     // 1/sqrt(64)

    int ntiles = qt + 1;            // causal: only tiles with kv0 <= q0+63
    for (int kt = 0; kt < ntiles; ++kt) {
        int kv0 = kt * 64;
        __syncthreads();            // protect Ks/Vs from prev-iter readers
        #pragma unroll
        for (int i = 0; i < 4; ++i) {
            int f = i * 256 + t;
            int row = f >> 4, col = (f & 15) * 4;
            *(float4*)&Ks[row][col] = *(const float4*)&K[(size_t)(kv0 + row) * KVCOLS + kvh * HD + col];
            *(float4*)&Vs[row][col] = *(const float4*)&V[(size_t)(kv0 + row) * KVCOLS + kvh * HD + col];
        }
        __syncthreads();

        // S[r][g*16+j] = Q[r]·K[g*16+j] * scale  (causal mask)
        float sc[16];
        #pragma unroll
        for (int j = 0; j < 16; ++j) sc[j] = 0.0f;
        #pragma unroll 4
        for (int d4 = 0; d4 < 16; ++d4) {
            float4 q4 = *(const float4*)&Qs[r][d4*4];
            #pragma unroll
            for (int j = 0; j < 16; ++j) {
                float4 k4 = *(const float4*)&Ks[g*16+j][d4*4];
                sc[j] += q4.x*k4.x + q4.y*k4.y + q4.z*k4.z + q4.w*k4.w;
            }
        }
        float mx = -1e30f;
        #pragma unroll
        for (int j = 0; j < 16; ++j) {
            int kc = kv0 + g*16 + j;
            sc[j] = (kc <= q0 + r) ? sc[j] * scale : -1e30f;
            mx = fmaxf(mx, sc[j]);
        }
        mx = fmaxf(mx, __shfl_xor(mx, 1, 4));
        mx = fmaxf(mx, __shfl_xor(mx, 2, 4));
        float mnew = fmaxf(m, mx);
        float alpha = __expf(m - mnew);
        float rs = 0.0f;
        #pragma unroll
        for (int j = 0; j < 16; ++j) {
            float p = __expf(sc[j] - mnew);
            Ps[r][g*16+j] = p;
            rs += p;
        }
        rs += __shfl_xor(rs, 1, 4);
        rs += __shfl_xor(rs, 2, 4);
        l = l * alpha + rs;
        m = mnew;
        #pragma unroll
        for (int i = 0; i < 16; ++i) o[i] *= alpha;
        // o[d] += sum_k P[r][k] * V[k][g*16+d]   (P row written by same wave)
        for (int k = 0; k < 64; ++k) {
            float p = Ps[r][k];
            #pragma unroll
            for (int d4 = 0; d4 < 4; ++d4) {
                float4 v4 = *(const float4*)&Vs[k][g*16 + d4*4];
                o[d4*4+0] += p * v4.x;
                o[d4*4+1] += p * v4.y;
                o[d4*4+2] += p * v4.z;
                o[d4*4+3] += p * v4.w;
            }
        }
    }
    float inv = 1.0f / l;
    #pragma unroll
    for (int d4 = 0; d4 < 4; ++d4) {
        float4 ov = make_float4(o[d4*4]*inv, o[d4*4+1]*inv, o[d4*4+2]*inv, o[d4*4+3]*inv);
        *(float4*)&O[(size_t)(q0 + r) * QCOLS + h * HD + g*16 + d4*4] = ov;
    }
}

// ---------------------------------------------------------------------------
// K3: output projection. attn[SEQ][2048] @ Wo[2048][2048] -> out
// ---------------------------------------------------------------------------
__global__ __launch_bounds__(256) void out_gemm_kernel(
    const float* __restrict__ A, const float* __restrict__ W, float* __restrict__ C)
{
    __shared__ float As[BK][LDT];
    __shared__ float Bs[BK][LDT];
    int n0 = blockIdx.x * BN;
    int m0 = blockIdx.y * BM;
    int t = threadIdx.x;
    int tr = t >> 4, tc = t & 15;
    int arow = t >> 2;
    int acol = (t & 3) * 4;
    int brow = t >> 4;
    int bcol = (t & 15) * 4;

    float acc[4][4] = {};
    for (int k0 = 0; k0 < HID; k0 += BK) {
        float4 a4 = *(const float4*)&A[(size_t)(m0 + arow) * HID + k0 + acol];
        float4 b4 = *(const float4*)&W[(size_t)(k0 + brow) * HID + n0 + bcol];
        As[acol+0][arow] = a4.x;
        As[acol+1][arow] = a4.y;
        As[acol+2][arow] = a4.z;
        As[acol+3][arow] = a4.w;
        *(float4*)&Bs[brow][bcol] = b4;
        __syncthreads();
        #pragma unroll
        for (int kk = 0; kk < BK; ++kk) {
            float4 av = *(const float4*)&As[kk][tr*4];
            float4 bv = *(const float4*)&Bs[kk][tc*4];
            float a[4] = {av.x, av.y, av.z, av.w};
            float b[4] = {bv.x, bv.y, bv.z, bv.w};
            #pragma unroll
            for (int i = 0; i < 4; ++i)
                #pragma unroll
                for (int j = 0; j < 4; ++j)
                    acc[i][j] += a[i] * b[j];
        }
        __syncthreads();
    }
    #pragma unroll
    for (int i = 0; i < 4; ++i) {
        float4 ov = make_float4(acc[i][0], acc[i][1], acc[i][2], acc[i][3]);
        *(float4*)&C[(size_t)(m0 + tr*4 + i) * HID + n0 + tc*4] = ov;
    }
}

// ---------------------------------------------------------------------------
extern "C" void kernel_launch(void* const* d_in, const int* in_sizes, int n_in,
                              void* d_out, int out_size, void* d_ws, size_t ws_size,
                              hipStream_t stream) {
    const float* X  = (const float*)d_in[0];
    // d_in[1] = attention_mask: causal by construction; masking applied directly
    const float* Wq = (const float*)d_in[2];
    const float* Wk = (const float*)d_in[3];
    const float* Wv = (const float*)d_in[4];
    const float* Wo = (const float*)d_in[5];
    float* out = (float*)d_out;

    float* ws   = (float*)d_ws;
    float* cosT = ws;                        // 2048*64
    float* sinT = cosT + SEQ*HD;             // 2048*64
    float* Q    = sinT + SEQ*HD;             // 2048*2048
    float* Kb   = Q    + (size_t)SEQ*QCOLS;  // 2048*512
    float* Vb   = Kb   + (size_t)SEQ*KVCOLS; // 2048*512
    float* attn = Vb   + (size_t)SEQ*KVCOLS; // 2048*2048

    rope_table_kernel<<<SEQ*HD/256, 256, 0, stream>>>(cosT, sinT);
    dim3 g1(NTOT/BN, SEQ/BM);
    qkv_kernel<<<g1, 256, 0, stream>>>(X, Wq, Wk, Wv, cosT, sinT, Q, Kb, Vb);
    dim3 g2(SEQ/64, NH);
    attn_kernel<<<g2, 256, 0, stream>>>(Q, Kb, Vb, attn);
    dim3 g3(HID/BN, SEQ/BM);
    out_gemm_kernel<<<g3, 256, 0, stream>>>(attn, Wo, out);
}

// Round 3
// 788.272 us; speedup vs baseline: 2.3544x; 2.3544x over previous
//
#include <hip/hip_runtime.h>
#include <math.h>

#define SEQ     2048
#define HID     2048
#define NH      32
#define NKV     8
#define HD      64
#define QCOLS   (NH*HD)          // 2048
#define KVCOLS  (NKV*HD)         // 512
#define NTOT    (QCOLS + 2*KVCOLS)

#define BM 64
#define BN 64
#define BK 16
#define LDT 68   // fp32 GEMM LDS stride

// attention LDS strides (bf16 elements)
#define LDK 72   // Ks[64][72]
#define LDV 76   // Vt[64][76]
#define LDP 72   // Ps per-wave [16][72] x4

typedef __attribute__((ext_vector_type(8))) short bf8_t;   // 8 bf16 (4 VGPRs)
typedef __attribute__((ext_vector_type(4))) float f4_t;    // C/D frag

__device__ inline unsigned short f2bf(float f) {
    union { float f; unsigned int u; } a; a.f = f;
    unsigned int u = a.u;
    u += 0x7fffu + ((u >> 16) & 1u);   // round-to-nearest-even (finite inputs)
    return (unsigned short)(u >> 16);
}

// ---------------------------------------------------------------------------
// K0: RoPE cos/sin tables. angle(s,d) = s * theta^(-(d&31)/32)
// ---------------------------------------------------------------------------
__global__ void rope_table_kernel(float* __restrict__ cosT, float* __restrict__ sinT) {
    int i = blockIdx.x * blockDim.x + threadIdx.x;   // 0 .. SEQ*HD-1
    int srow = i >> 6;
    int d = i & 63;
    float inv = powf(500000.0f, -(float)(d & 31) / 32.0f);
    float a = (float)srow * inv;
    cosT[i] = cosf(a);
    sinT[i] = sinf(a);
}

// ---------------------------------------------------------------------------
// K1: fused QKV projection GEMM (fp32 compute) with RoPE epilogue; bf16 output.
// ---------------------------------------------------------------------------
__global__ __launch_bounds__(256) void qkv_kernel(
    const float* __restrict__ X,  const float* __restrict__ Wq,
    const float* __restrict__ Wk, const float* __restrict__ Wv,
    const float* __restrict__ cosT, const float* __restrict__ sinT,
    unsigned short* __restrict__ Q, unsigned short* __restrict__ K,
    unsigned short* __restrict__ V)
{
    __shared__ float As[BK][LDT];   // transposed A tile: As[k][m]
    __shared__ float Bs[BK][LDT];
    int n0 = blockIdx.x * BN;
    int m0 = blockIdx.y * BM;
    const float* B; int ldb; int bcol0; int region; // 0=Q 1=K 2=V
    if (n0 < QCOLS)              { B = Wq; ldb = QCOLS;  bcol0 = n0;                  region = 0; }
    else if (n0 < QCOLS+KVCOLS)  { B = Wk; ldb = KVCOLS; bcol0 = n0 - QCOLS;          region = 1; }
    else                         { B = Wv; ldb = KVCOLS; bcol0 = n0 - QCOLS - KVCOLS; region = 2; }

    int t = threadIdx.x;
    int tr = t >> 4, tc = t & 15;
    int arow = t >> 2;
    int acol = (t & 3) * 4;
    int brow = t >> 4;
    int bcol = (t & 15) * 4;

    float acc[4][4] = {};
    for (int k0 = 0; k0 < HID; k0 += BK) {
        float4 a4 = *(const float4*)&X[(size_t)(m0 + arow) * HID + k0 + acol];
        float4 b4 = *(const float4*)&B[(size_t)(k0 + brow) * ldb + bcol0 + bcol];
        As[acol+0][arow] = a4.x;
        As[acol+1][arow] = a4.y;
        As[acol+2][arow] = a4.z;
        As[acol+3][arow] = a4.w;
        *(float4*)&Bs[brow][bcol] = b4;
        __syncthreads();
        #pragma unroll
        for (int kk = 0; kk < BK; ++kk) {
            float4 av = *(const float4*)&As[kk][tr*4];
            float4 bv = *(const float4*)&Bs[kk][tc*4];
            float a[4] = {av.x, av.y, av.z, av.w};
            float b[4] = {bv.x, bv.y, bv.z, bv.w};
            #pragma unroll
            for (int i = 0; i < 4; ++i)
                #pragma unroll
                for (int j = 0; j < 4; ++j)
                    acc[i][j] += a[i] * b[j];
        }
        __syncthreads();
    }

    int nbase = n0 + tc * 4;
    int d0 = nbase & 63;
    #pragma unroll
    for (int i = 0; i < 4; ++i) {
        int srow = m0 + tr * 4 + i;
        float o[4] = {acc[i][0], acc[i][1], acc[i][2], acc[i][3]};
        if (region != 2) {
            #pragma unroll
            for (int p = 0; p < 2; ++p) {
                float x1 = o[2*p], x2 = o[2*p+1];
                int d = d0 + 2*p;
                float c0 = cosT[srow*HD + d],   s0 = sinT[srow*HD + d];
                float c1 = cosT[srow*HD + d+1], s1 = sinT[srow*HD + d+1];
                o[2*p]   = x1 * c0 - x2 * s0;
                o[2*p+1] = x2 * c1 + x1 * s1;
            }
        }
        ushort4 ov;
        ov.x = f2bf(o[0]); ov.y = f2bf(o[1]); ov.z = f2bf(o[2]); ov.w = f2bf(o[3]);
        if (region == 0)      *(ushort4*)&Q[(size_t)srow*QCOLS  + nbase] = ov;
        else if (region == 1) *(ushort4*)&K[(size_t)srow*KVCOLS + (nbase - QCOLS)] = ov;
        else                  *(ushort4*)&V[(size_t)srow*KVCOLS + (nbase - QCOLS - KVCOLS)] = ov;
    }
}

// ---------------------------------------------------------------------------
// K2: causal flash attention, bf16 MFMA (16x16x32).
// Block = 4 waves x 64 lanes = one 64-row q-tile of one head.
// Wave w owns q-rows [q0+16w, q0+16w+16). Per kv-tile of 64:
//   S = Q K^T (8 mfma), wave-parallel online softmax, P->LDS(bf16), PV (8 mfma).
// C/D frag layout (verified m89/m91): col=lane&15, row=(lane>>4)*4+reg.
// A/B frag: idx=lane&15 (M or N), k=8*(lane>>4)+j (+32*kc).
// ---------------------------------------------------------------------------
__global__ __launch_bounds__(256) void attn_mfma_kernel(
    const unsigned short* __restrict__ Q, const unsigned short* __restrict__ K,
    const unsigned short* __restrict__ V, float* __restrict__ O)
{
    __shared__ unsigned short Ks[64 * LDK];
    __shared__ unsigned short Vt[64 * LDV];   // transposed: Vt[d][kv]
    __shared__ unsigned short Ps[64 * LDP];   // per-wave 16-row regions

    int qt = blockIdx.x;
    int h  = blockIdx.y;
    int q0 = qt * 64;
    int kvh = h >> 2;
    int t = threadIdx.x;
    int wid = t >> 6, lane = t & 63;
    int l16 = lane & 15, g4 = lane >> 4;
    int qw = q0 + wid * 16;                    // wave's q-row base
    unsigned short* PsW = &Ps[wid * 16 * LDP];

    // Q A-frags (global bf16, once): qa[kc][j] = Q[qw+l16][32*kc + 8*g4 + j]
    bf8_t qa[2];
    qa[0] = *(const bf8_t*)&Q[(size_t)(qw + l16) * QCOLS + h * HD + 8 * g4];
    qa[1] = *(const bf8_t*)&Q[(size_t)(qw + l16) * QCOLS + h * HD + 32 + 8 * g4];

    f4_t o[4];
    #pragma unroll
    for (int n = 0; n < 4; ++n) o[n] = (f4_t){0.f, 0.f, 0.f, 0.f};
    float m_r[4] = {-1e30f, -1e30f, -1e30f, -1e30f};
    float l_r[4] = {0.f, 0.f, 0.f, 0.f};

    int ntiles = qt + 1;
    for (int kt = 0; kt < ntiles; ++kt) {
        int kv0 = kt * 64;
        __syncthreads();   // prior iter's PV reads done before restage
        // stage K row-major [kv][d] and V transposed [d][kv]
        #pragma unroll
        for (int i = 0; i < 2; ++i) {
            int c = t + i * 256;             // 16B chunk id, 512 total
            int row = c >> 3, col16 = c & 7;
            size_t gb = (size_t)(kv0 + row) * KVCOLS + kvh * HD + col16 * 8;
            bf8_t k8 = *(const bf8_t*)&K[gb];
            *(bf8_t*)&Ks[row * LDK + col16 * 8] = k8;
            bf8_t v8 = *(const bf8_t*)&V[gb];
            #pragma unroll
            for (int j = 0; j < 8; ++j)
                Vt[(col16 * 8 + j) * LDV + row] = (unsigned short)v8[j];
        }
        __syncthreads();

        // S = Q K^T : s[n] covers k-cols n*16..n*16+15
        f4_t s[4];
        #pragma unroll
        for (int n = 0; n < 4; ++n) s[n] = (f4_t){0.f, 0.f, 0.f, 0.f};
        #pragma unroll
        for (int kc = 0; kc < 2; ++kc) {
            #pragma unroll
            for (int n = 0; n < 4; ++n) {
                bf8_t kb = *(const bf8_t*)&Ks[(n * 16 + l16) * LDK + 32 * kc + 8 * g4];
                s[n] = __builtin_amdgcn_mfma_f32_16x16x32_bf16(qa[kc], kb, s[n], 0, 0, 0);
            }
        }

        bool diag = (kt == qt);
        // online softmax, one q-row per (g4, reg r); 16 lanes share a row
        #pragma unroll
        for (int r = 0; r < 4; ++r) {
            int qg = qw + g4 * 4 + r;
            float v0[4];
            float mx = -1e30f;
            #pragma unroll
            for (int n = 0; n < 4; ++n) {
                float x = s[n][r] * 0.125f;
                if (diag) { int kc_ = kv0 + n * 16 + l16; if (kc_ > qg) x = -1e30f; }
                v0[n] = x;
                mx = fmaxf(mx, x);
            }
            mx = fmaxf(mx, __shfl_xor(mx, 1, 16));
            mx = fmaxf(mx, __shfl_xor(mx, 2, 16));
            mx = fmaxf(mx, __shfl_xor(mx, 4, 16));
            mx = fmaxf(mx, __shfl_xor(mx, 8, 16));
            float mnew = fmaxf(m_r[r], mx);
            float alpha = __expf(m_r[r] - mnew);
            float rs = 0.f;
            #pragma unroll
            for (int n = 0; n < 4; ++n) {
                float p = __expf(v0[n] - mnew);
                rs += p;
                PsW[(g4 * 4 + r) * LDP + n * 16 + l16] = f2bf(p);
            }
            rs += __shfl_xor(rs, 1, 16);
            rs += __shfl_xor(rs, 2, 16);
            rs += __shfl_xor(rs, 4, 16);
            rs += __shfl_xor(rs, 8, 16);
            l_r[r] = l_r[r] * alpha + rs;
            m_r[r] = mnew;
            #pragma unroll
            for (int n = 0; n < 4; ++n) o[n][r] *= alpha;
        }

        // PV: o += P @ V   (P wave-local; same-wave DS ops are in-order)
        #pragma unroll
        for (int kc = 0; kc < 2; ++kc) {
            bf8_t pa = *(const bf8_t*)&PsW[l16 * LDP + 32 * kc + 8 * g4];
            #pragma unroll
            for (int n = 0; n < 4; ++n) {
                bf8_t vb = *(const bf8_t*)&Vt[(n * 16 + l16) * LDV + 32 * kc + 8 * g4];
                o[n] = __builtin_amdgcn_mfma_f32_16x16x32_bf16(pa, vb, o[n], 0, 0, 0);
            }
        }
    }

    #pragma unroll
    for (int r = 0; r < 4; ++r) {
        float inv = 1.0f / l_r[r];
        int qg = qw + g4 * 4 + r;
        #pragma unroll
        for (int n = 0; n < 4; ++n)
            O[(size_t)qg * QCOLS + h * HD + n * 16 + l16] = o[n][r] * inv;
    }
}

// ---------------------------------------------------------------------------
// K3: output projection (fp32). attn[SEQ][2048] @ Wo[2048][2048] -> out
// ---------------------------------------------------------------------------
__global__ __launch_bounds__(256) void out_gemm_kernel(
    const float* __restrict__ A, const float* __restrict__ W, float* __restrict__ C)
{
    __shared__ float As[BK][LDT];
    __shared__ float Bs[BK][LDT];
    int n0 = blockIdx.x * BN;
    int m0 = blockIdx.y * BM;
    int t = threadIdx.x;
    int tr = t >> 4, tc = t & 15;
    int arow = t >> 2;
    int acol = (t & 3) * 4;
    int brow = t >> 4;
    int bcol = (t & 15) * 4;

    float acc[4][4] = {};
    for (int k0 = 0; k0 < HID; k0 += BK) {
        float4 a4 = *(const float4*)&A[(size_t)(m0 + arow) * HID + k0 + acol];
        float4 b4 = *(const float4*)&W[(size_t)(k0 + brow) * HID + n0 + bcol];
        As[acol+0][arow] = a4.x;
        As[acol+1][arow] = a4.y;
        As[acol+2][arow] = a4.z;
        As[acol+3][arow] = a4.w;
        *(float4*)&Bs[brow][bcol] = b4;
        __syncthreads();
        #pragma unroll
        for (int kk = 0; kk < BK; ++kk) {
            float4 av = *(const float4*)&As[kk][tr*4];
            float4 bv = *(const float4*)&Bs[kk][tc*4];
            float a[4] = {av.x, av.y, av.z, av.w};
            float b[4] = {bv.x, bv.y, bv.z, bv.w};
            #pragma unroll
            for (int i = 0; i < 4; ++i)
                #pragma unroll
                for (int j = 0; j < 4; ++j)
                    acc[i][j] += a[i] * b[j];
        }
        __syncthreads();
    }
    #pragma unroll
    for (int i = 0; i < 4; ++i) {
        float4 ov = make_float4(acc[i][0], acc[i][1], acc[i][2], acc[i][3]);
        *(float4*)&C[(size_t)(m0 + tr*4 + i) * HID + n0 + tc*4] = ov;
    }
}

// ---------------------------------------------------------------------------
extern "C" void kernel_launch(void* const* d_in, const int* in_sizes, int n_in,
                              void* d_out, int out_size, void* d_ws, size_t ws_size,
                              hipStream_t stream) {
    const float* X  = (const float*)d_in[0];
    // d_in[1] = attention_mask: causal by construction; applied analytically
    const float* Wq = (const float*)d_in[2];
    const float* Wk = (const float*)d_in[3];
    const float* Wv = (const float*)d_in[4];
    const float* Wo = (const float*)d_in[5];
    float* out = (float*)d_out;

    float* ws   = (float*)d_ws;
    float* cosT = ws;                                     // 2048*64 f32
    float* sinT = cosT + SEQ*HD;                          // 2048*64 f32
    unsigned short* Qb = (unsigned short*)(sinT + SEQ*HD);        // 2048*2048 bf16
    unsigned short* Kb = Qb + (size_t)SEQ*QCOLS;                  // 2048*512 bf16
    unsigned short* Vb = Kb + (size_t)SEQ*KVCOLS;                 // 2048*512 bf16
    float* attn = (float*)(Vb + (size_t)SEQ*KVCOLS);              // 2048*2048 f32

    rope_table_kernel<<<SEQ*HD/256, 256, 0, stream>>>(cosT, sinT);
    dim3 g1(NTOT/BN, SEQ/BM);
    qkv_kernel<<<g1, 256, 0, stream>>>(X, Wq, Wk, Wv, cosT, sinT, Qb, Kb, Vb);
    dim3 g2(SEQ/64, NH);
    attn_mfma_kernel<<<g2, 256, 0, stream>>>(Qb, Kb, Vb, attn);
    dim3 g3(HID/BN, SEQ/BM);
    out_gemm_kernel<<<g3, 256, 0, stream>>>(attn, Wo, out);
}

// Round 4
// 368.602 us; speedup vs baseline: 5.0351x; 2.1385x over previous
//
#include <hip/hip_runtime.h>
#include <math.h>

#define SEQ     2048
#define HID     2048
#define NH      32
#define NKV     8
#define HD      64
#define QCOLS   (NH*HD)          // 2048
#define KVCOLS  (NKV*HD)         // 512

// attention LDS strides (bf16 elements)
#define LDK 72   // Ks[64][72]
#define LDV 76   // Vt[64][76]
#define LDP 72   // Ps per-wave [16][72] x4

// GEMM LDS row stride (bf16 elements): 32 data + 4 pad = 72B rows (~2-way conflicts)
#define LDG 36

typedef __attribute__((ext_vector_type(8))) short bf8_t;   // 8 bf16 (4 VGPRs)
typedef __attribute__((ext_vector_type(4))) float f4_t;    // C/D frag

__device__ inline unsigned short f2bf(float f) {
    union { float f; unsigned int u; } a; a.f = f;
    unsigned int u = a.u;
    u += 0x7fffu + ((u >> 16) & 1u);   // round-to-nearest-even (finite inputs)
    return (unsigned short)(u >> 16);
}

// ---------------------------------------------------------------------------
// K0: RoPE cos/sin tables. angle(s,d) = s * theta^(-(d&31)/32)
// ---------------------------------------------------------------------------
__global__ void rope_table_kernel(float* __restrict__ cosT, float* __restrict__ sinT) {
    int i = blockIdx.x * blockDim.x + threadIdx.x;   // 0 .. SEQ*HD-1
    int srow = i >> 6;
    int d = i & 63;
    float inv = powf(500000.0f, -(float)(d & 31) / 32.0f);
    float a = (float)srow * inv;
    cosT[i] = cosf(a);
    sinT[i] = sinf(a);
}

// ---------------------------------------------------------------------------
// K0b: X fp32 -> bf16 (row-major unchanged)
// ---------------------------------------------------------------------------
__global__ void convert_x_kernel(const float* __restrict__ X, unsigned short* __restrict__ Xb) {
    int i = blockIdx.x * blockDim.x + threadIdx.x;   // float4 index
    float4 v = *(const float4*)&X[(size_t)i * 4];
    ushort4 o;
    o.x = f2bf(v.x); o.y = f2bf(v.y); o.z = f2bf(v.z); o.w = f2bf(v.w);
    *(ushort4*)&Xb[(size_t)i * 4] = o;
}

// ---------------------------------------------------------------------------
// K0c: weight transpose + bf16: W[K=2048][N] fp32 -> WT[noff+n][k] bf16 (ld 2048)
// ---------------------------------------------------------------------------
__global__ __launch_bounds__(256) void transpose_w_kernel(
    const float* __restrict__ W, int N, unsigned short* __restrict__ WT, int noff)
{
    __shared__ float tile[32][33];
    int n0 = blockIdx.x * 32, k0 = blockIdx.y * 32;
    int t = threadIdx.x;
    int tx = t & 31, ty = t >> 5;   // ty 0..7
    #pragma unroll
    for (int i = 0; i < 4; ++i) {
        int k = ty + i * 8;
        tile[k][tx] = W[(size_t)(k0 + k) * N + n0 + tx];
    }
    __syncthreads();
    #pragma unroll
    for (int i = 0; i < 4; ++i) {
        int n = ty + i * 8;
        WT[(size_t)(noff + n0 + n) * HID + k0 + tx] = f2bf(tile[tx][n]);
    }
}

// ---------------------------------------------------------------------------
// K1: QKV projection, bf16 MFMA. C = Xb @ WT^T ; RoPE epilogue on Q/K cols.
// 128x128 tile, 4 waves (2x2), each wave 64x64 = 4x4 frags of 16x16x32.
// ---------------------------------------------------------------------------
__global__ __launch_bounds__(256) void qkv_mfma_kernel(
    const unsigned short* __restrict__ A, const unsigned short* __restrict__ BT,
    const float* __restrict__ cosT, const float* __restrict__ sinT,
    unsigned short* __restrict__ Q, unsigned short* __restrict__ Ko,
    unsigned short* __restrict__ Vo)
{
    __shared__ unsigned short As[128 * LDG];
    __shared__ unsigned short Bs[128 * LDG];
    int n0 = blockIdx.x * 128, m0 = blockIdx.y * 128;
    int t = threadIdx.x;
    int lane = t & 63, wid = t >> 6;
    int l16 = lane & 15, g4 = lane >> 4;
    int wr = wid >> 1, wc = wid & 1;

    f4_t acc[4][4];
    #pragma unroll
    for (int mi = 0; mi < 4; ++mi)
        #pragma unroll
        for (int ni = 0; ni < 4; ++ni) acc[mi][ni] = (f4_t){0.f, 0.f, 0.f, 0.f};

    int r0 = t >> 2, c0 = (t & 3) * 8;      // staging: row 0..63, col {0,8,16,24}
    const unsigned short* Ap = &A[(size_t)(m0 + r0) * HID + c0];
    const unsigned short* Bp = &BT[(size_t)(n0 + r0) * HID + c0];

    for (int k0 = 0; k0 < HID; k0 += 32) {
        bf8_t a0 = *(const bf8_t*)(Ap + k0);
        bf8_t a1 = *(const bf8_t*)(Ap + (size_t)64 * HID + k0);
        bf8_t b0 = *(const bf8_t*)(Bp + k0);
        bf8_t b1 = *(const bf8_t*)(Bp + (size_t)64 * HID + k0);
        __syncthreads();
        *(bf8_t*)&As[r0 * LDG + c0] = a0;
        *(bf8_t*)&As[(r0 + 64) * LDG + c0] = a1;
        *(bf8_t*)&Bs[r0 * LDG + c0] = b0;
        *(bf8_t*)&Bs[(r0 + 64) * LDG + c0] = b1;
        __syncthreads();
        bf8_t af[4], bfr[4];
        #pragma unroll
        for (int mi = 0; mi < 4; ++mi)
            af[mi] = *(const bf8_t*)&As[(wr * 64 + mi * 16 + l16) * LDG + 8 * g4];
        #pragma unroll
        for (int ni = 0; ni < 4; ++ni)
            bfr[ni] = *(const bf8_t*)&Bs[(wc * 64 + ni * 16 + l16) * LDG + 8 * g4];
        #pragma unroll
        for (int mi = 0; mi < 4; ++mi)
            #pragma unroll
            for (int ni = 0; ni < 4; ++ni)
                acc[mi][ni] = __builtin_amdgcn_mfma_f32_16x16x32_bf16(af[mi], bfr[ni], acc[mi][ni], 0, 0, 0);
    }

    // epilogue: C/D layout col=l16, row=g4*4+r. RoPE partner col = n^1 = lane^1.
    #pragma unroll
    for (int ni = 0; ni < 4; ++ni) {
        int n = n0 + wc * 64 + ni * 16 + l16;
        int d = n & 63;
        int odd = n & 1;
        #pragma unroll
        for (int mi = 0; mi < 4; ++mi) {
            #pragma unroll
            for (int r = 0; r < 4; ++r) {
                float x = acc[mi][ni][r];
                float xp = __shfl_xor(x, 1);
                int s = m0 + wr * 64 + mi * 16 + g4 * 4 + r;
                float val;
                if (n < QCOLS + KVCOLS) {
                    float cv = cosT[s * HD + d], sv = sinT[s * HD + d];
                    val = odd ? x * cv + xp * sv : x * cv - xp * sv;
                } else val = x;
                unsigned short ob = f2bf(val);
                if (n < QCOLS)                   Q[(size_t)s * QCOLS + n] = ob;
                else if (n < QCOLS + KVCOLS)     Ko[(size_t)s * KVCOLS + n - QCOLS] = ob;
                else                             Vo[(size_t)s * KVCOLS + n - QCOLS - KVCOLS] = ob;
            }
        }
    }
}

// ---------------------------------------------------------------------------
// K3: output projection, bf16 MFMA. out = attnb @ WoT^T (fp32 out).
// ---------------------------------------------------------------------------
__global__ __launch_bounds__(256) void out_mfma_kernel(
    const unsigned short* __restrict__ A, const unsigned short* __restrict__ BT,
    float* __restrict__ C)
{
    __shared__ unsigned short As[128 * LDG];
    __shared__ unsigned short Bs[128 * LDG];
    int n0 = blockIdx.x * 128, m0 = blockIdx.y * 128;
    int t = threadIdx.x;
    int lane = t & 63, wid = t >> 6;
    int l16 = lane & 15, g4 = lane >> 4;
    int wr = wid >> 1, wc = wid & 1;

    f4_t acc[4][4];
    #pragma unroll
    for (int mi = 0; mi < 4; ++mi)
        #pragma unroll
        for (int ni = 0; ni < 4; ++ni) acc[mi][ni] = (f4_t){0.f, 0.f, 0.f, 0.f};

    int r0 = t >> 2, c0 = (t & 3) * 8;
    const unsigned short* Ap = &A[(size_t)(m0 + r0) * HID + c0];
    const unsigned short* Bp = &BT[(size_t)(n0 + r0) * HID + c0];

    for (int k0 = 0; k0 < HID; k0 += 32) {
        bf8_t a0 = *(const bf8_t*)(Ap + k0);
        bf8_t a1 = *(const bf8_t*)(Ap + (size_t)64 * HID + k0);
        bf8_t b0 = *(const bf8_t*)(Bp + k0);
        bf8_t b1 = *(const bf8_t*)(Bp + (size_t)64 * HID + k0);
        __syncthreads();
        *(bf8_t*)&As[r0 * LDG + c0] = a0;
        *(bf8_t*)&As[(r0 + 64) * LDG + c0] = a1;
        *(bf8_t*)&Bs[r0 * LDG + c0] = b0;
        *(bf8_t*)&Bs[(r0 + 64) * LDG + c0] = b1;
        __syncthreads();
        bf8_t af[4], bfr[4];
        #pragma unroll
        for (int mi = 0; mi < 4; ++mi)
            af[mi] = *(const bf8_t*)&As[(wr * 64 + mi * 16 + l16) * LDG + 8 * g4];
        #pragma unroll
        for (int ni = 0; ni < 4; ++ni)
            bfr[ni] = *(const bf8_t*)&Bs[(wc * 64 + ni * 16 + l16) * LDG + 8 * g4];
        #pragma unroll
        for (int mi = 0; mi < 4; ++mi)
            #pragma unroll
            for (int ni = 0; ni < 4; ++ni)
                acc[mi][ni] = __builtin_amdgcn_mfma_f32_16x16x32_bf16(af[mi], bfr[ni], acc[mi][ni], 0, 0, 0);
    }

    #pragma unroll
    for (int ni = 0; ni < 4; ++ni) {
        int n = n0 + wc * 64 + ni * 16 + l16;
        #pragma unroll
        for (int mi = 0; mi < 4; ++mi) {
            #pragma unroll
            for (int r = 0; r < 4; ++r) {
                int s = m0 + wr * 64 + mi * 16 + g4 * 4 + r;
                C[(size_t)s * HID + n] = acc[mi][ni][r];
            }
        }
    }
}

// ---------------------------------------------------------------------------
// K2: causal flash attention, bf16 MFMA (16x16x32). bf16 output.
// ---------------------------------------------------------------------------
__global__ __launch_bounds__(256) void attn_mfma_kernel(
    const unsigned short* __restrict__ Q, const unsigned short* __restrict__ K,
    const unsigned short* __restrict__ V, unsigned short* __restrict__ O)
{
    __shared__ unsigned short Ks[64 * LDK];
    __shared__ unsigned short Vt[64 * LDV];   // transposed: Vt[d][kv]
    __shared__ unsigned short Ps[64 * LDP];   // per-wave 16-row regions

    int qt = blockIdx.x;
    int h  = blockIdx.y;
    int q0 = qt * 64;
    int kvh = h >> 2;
    int t = threadIdx.x;
    int wid = t >> 6, lane = t & 63;
    int l16 = lane & 15, g4 = lane >> 4;
    int qw = q0 + wid * 16;
    unsigned short* PsW = &Ps[wid * 16 * LDP];

    bf8_t qa[2];
    qa[0] = *(const bf8_t*)&Q[(size_t)(qw + l16) * QCOLS + h * HD + 8 * g4];
    qa[1] = *(const bf8_t*)&Q[(size_t)(qw + l16) * QCOLS + h * HD + 32 + 8 * g4];

    f4_t o[4];
    #pragma unroll
    for (int n = 0; n < 4; ++n) o[n] = (f4_t){0.f, 0.f, 0.f, 0.f};
    float m_r[4] = {-1e30f, -1e30f, -1e30f, -1e30f};
    float l_r[4] = {0.f, 0.f, 0.f, 0.f};

    int ntiles = qt + 1;
    for (int kt = 0; kt < ntiles; ++kt) {
        int kv0 = kt * 64;
        __syncthreads();
        #pragma unroll
        for (int i = 0; i < 2; ++i) {
            int c = t + i * 256;
            int row = c >> 3, col16 = c & 7;
            size_t gb = (size_t)(kv0 + row) * KVCOLS + kvh * HD + col16 * 8;
            bf8_t k8 = *(const bf8_t*)&K[gb];
            *(bf8_t*)&Ks[row * LDK + col16 * 8] = k8;
            bf8_t v8 = *(const bf8_t*)&V[gb];
            #pragma unroll
            for (int j = 0; j < 8; ++j)
                Vt[(col16 * 8 + j) * LDV + row] = (unsigned short)v8[j];
        }
        __syncthreads();

        f4_t s[4];
        #pragma unroll
        for (int n = 0; n < 4; ++n) s[n] = (f4_t){0.f, 0.f, 0.f, 0.f};
        #pragma unroll
        for (int kc = 0; kc < 2; ++kc) {
            #pragma unroll
            for (int n = 0; n < 4; ++n) {
                bf8_t kb = *(const bf8_t*)&Ks[(n * 16 + l16) * LDK + 32 * kc + 8 * g4];
                s[n] = __builtin_amdgcn_mfma_f32_16x16x32_bf16(qa[kc], kb, s[n], 0, 0, 0);
            }
        }

        bool diag = (kt == qt);
        #pragma unroll
        for (int r = 0; r < 4; ++r) {
            int qg = qw + g4 * 4 + r;
            float v0[4];
            float mx = -1e30f;
            #pragma unroll
            for (int n = 0; n < 4; ++n) {
                float x = s[n][r] * 0.125f;
                if (diag) { int kc_ = kv0 + n * 16 + l16; if (kc_ > qg) x = -1e30f; }
                v0[n] = x;
                mx = fmaxf(mx, x);
            }
            mx = fmaxf(mx, __shfl_xor(mx, 1, 16));
            mx = fmaxf(mx, __shfl_xor(mx, 2, 16));
            mx = fmaxf(mx, __shfl_xor(mx, 4, 16));
            mx = fmaxf(mx, __shfl_xor(mx, 8, 16));
            float mnew = fmaxf(m_r[r], mx);
            float alpha = __expf(m_r[r] - mnew);
            float rs = 0.f;
            #pragma unroll
            for (int n = 0; n < 4; ++n) {
                float p = __expf(v0[n] - mnew);
                rs += p;
                PsW[(g4 * 4 + r) * LDP + n * 16 + l16] = f2bf(p);
            }
            rs += __shfl_xor(rs, 1, 16);
            rs += __shfl_xor(rs, 2, 16);
            rs += __shfl_xor(rs, 4, 16);
            rs += __shfl_xor(rs, 8, 16);
            l_r[r] = l_r[r] * alpha + rs;
            m_r[r] = mnew;
            #pragma unroll
            for (int n = 0; n < 4; ++n) o[n][r] *= alpha;
        }

        #pragma unroll
        for (int kc = 0; kc < 2; ++kc) {
            bf8_t pa = *(const bf8_t*)&PsW[l16 * LDP + 32 * kc + 8 * g4];
            #pragma unroll
            for (int n = 0; n < 4; ++n) {
                bf8_t vb = *(const bf8_t*)&Vt[(n * 16 + l16) * LDV + 32 * kc + 8 * g4];
                o[n] = __builtin_amdgcn_mfma_f32_16x16x32_bf16(pa, vb, o[n], 0, 0, 0);
            }
        }
    }

    #pragma unroll
    for (int r = 0; r < 4; ++r) {
        float inv = 1.0f / l_r[r];
        int qg = qw + g4 * 4 + r;
        #pragma unroll
        for (int n = 0; n < 4; ++n)
            O[(size_t)qg * QCOLS + h * HD + n * 16 + l16] = f2bf(o[n][r] * inv);
    }
}

// ---------------------------------------------------------------------------
extern "C" void kernel_launch(void* const* d_in, const int* in_sizes, int n_in,
                              void* d_out, int out_size, void* d_ws, size_t ws_size,
                              hipStream_t stream) {
    const float* X  = (const float*)d_in[0];
    // d_in[1] = attention_mask: causal by construction; applied analytically
    const float* Wq = (const float*)d_in[2];
    const float* Wk = (const float*)d_in[3];
    const float* Wv = (const float*)d_in[4];
    const float* Wo = (const float*)d_in[5];
    float* out = (float*)d_out;

    float* ws   = (float*)d_ws;
    float* cosT = ws;                                     // 2048*64 f32
    float* sinT = cosT + SEQ*HD;                          // 2048*64 f32
    unsigned short* Xb  = (unsigned short*)(sinT + SEQ*HD);   // 2048*2048 bf16
    unsigned short* WT  = Xb + (size_t)SEQ*HID;               // 3072*2048 bf16 (Wq|Wk|Wv)^T
    unsigned short* WoT = WT + (size_t)3072*HID;              // 2048*2048 bf16
    unsigned short* Qb  = WoT + (size_t)HID*HID;              // 2048*2048
    unsigned short* Kb  = Qb + (size_t)SEQ*QCOLS;             // 2048*512
    unsigned short* Vb  = Kb + (size_t)SEQ*KVCOLS;            // 2048*512
    unsigned short* attnb = Vb + (size_t)SEQ*KVCOLS;          // 2048*2048

    rope_table_kernel<<<SEQ*HD/256, 256, 0, stream>>>(cosT, sinT);
    convert_x_kernel<<<SEQ*HID/4/256, 256, 0, stream>>>(X, Xb);
    transpose_w_kernel<<<dim3(QCOLS/32,  HID/32), 256, 0, stream>>>(Wq, QCOLS,  WT, 0);
    transpose_w_kernel<<<dim3(KVCOLS/32, HID/32), 256, 0, stream>>>(Wk, KVCOLS, WT, QCOLS);
    transpose_w_kernel<<<dim3(KVCOLS/32, HID/32), 256, 0, stream>>>(Wv, KVCOLS, WT, QCOLS + KVCOLS);
    transpose_w_kernel<<<dim3(HID/32,    HID/32), 256, 0, stream>>>(Wo, HID,    WoT, 0);

    dim3 g1(3072/128, SEQ/128);
    qkv_mfma_kernel<<<g1, 256, 0, stream>>>(Xb, WT, cosT, sinT, Qb, Kb, Vb);
    dim3 g2(SEQ/64, NH);
    attn_mfma_kernel<<<g2, 256, 0, stream>>>(Qb, Kb, Vb, attnb);
    dim3 g3(HID/128, SEQ/128);
    out_mfma_kernel<<<g3, 256, 0, stream>>>(attnb, WoT, out);
}

// Round 5
// 367.847 us; speedup vs baseline: 5.0454x; 1.0021x over previous
//
#include <hip/hip_runtime.h>
#include <math.h>

#define SEQ     2048
#define HID     2048
#define NH      32
#define NKV     8
#define HD      64
#define QCOLS   (NH*HD)          // 2048
#define KVCOLS  (NKV*HD)         // 512

// attention LDS strides (bf16 elements)
#define LDK 72   // Ks[64][72]
#define LDV 76   // Vt[64][76]
#define LDP 72   // Ps per-wave [16][72] x4

typedef __attribute__((ext_vector_type(8))) short bf8_t;   // 8 bf16 (4 VGPRs)
typedef __attribute__((ext_vector_type(4))) float f4_t;    // C/D frag

typedef __attribute__((address_space(1))) const unsigned int glb_u32;
typedef __attribute__((address_space(3))) unsigned int lds_u32;

__device__ inline unsigned short f2bf(float f) {
    union { float f; unsigned int u; } a; a.f = f;
    unsigned int u = a.u;
    u += 0x7fffu + ((u >> 16) & 1u);   // round-to-nearest-even (finite inputs)
    return (unsigned short)(u >> 16);
}

// ---------------------------------------------------------------------------
// K0: RoPE cos/sin tables.
// ---------------------------------------------------------------------------
__global__ void rope_table_kernel(float* __restrict__ cosT, float* __restrict__ sinT) {
    int i = blockIdx.x * blockDim.x + threadIdx.x;   // 0 .. SEQ*HD-1
    int srow = i >> 6;
    int d = i & 63;
    float inv = powf(500000.0f, -(float)(d & 31) / 32.0f);
    float a = (float)srow * inv;
    cosT[i] = cosf(a);
    sinT[i] = sinf(a);
}

// ---------------------------------------------------------------------------
// K0b: X fp32 -> bf16
// ---------------------------------------------------------------------------
__global__ void convert_x_kernel(const float* __restrict__ X, unsigned short* __restrict__ Xb) {
    int i = blockIdx.x * blockDim.x + threadIdx.x;
    float4 v = *(const float4*)&X[(size_t)i * 4];
    ushort4 o;
    o.x = f2bf(v.x); o.y = f2bf(v.y); o.z = f2bf(v.z); o.w = f2bf(v.w);
    *(ushort4*)&Xb[(size_t)i * 4] = o;
}

// ---------------------------------------------------------------------------
// K0c: weight transpose + bf16: W[K=2048][N] fp32 -> WT[noff+n][k] bf16
// ---------------------------------------------------------------------------
__global__ __launch_bounds__(256) void transpose_w_kernel(
    const float* __restrict__ W, int N, unsigned short* __restrict__ WT, int noff)
{
    __shared__ float tile[32][33];
    int n0 = blockIdx.x * 32, k0 = blockIdx.y * 32;
    int t = threadIdx.x;
    int tx = t & 31, ty = t >> 5;
    #pragma unroll
    for (int i = 0; i < 4; ++i) {
        int k = ty + i * 8;
        tile[k][tx] = W[(size_t)(k0 + k) * N + n0 + tx];
    }
    __syncthreads();
    #pragma unroll
    for (int i = 0; i < 4; ++i) {
        int n = ty + i * 8;
        WT[(size_t)(noff + n0 + n) * HID + k0 + tx] = f2bf(tile[tx][n]);
    }
}

// ===========================================================================
// GEMM: 128(M)x64(N) tile, BK=64, global_load_lds staging, linear LDS.
// 4 waves as 2x2: wave = 64M x 32N = 4x2 frags of mfma_f32_16x16x32_bf16.
// ===========================================================================
// A-tile [128][64] bf16 (16KB), B-tile [64][64] bf16 (8KB), both [row][k].

__device__ __forceinline__ void gemm_core(
    const unsigned short* __restrict__ A, const unsigned short* __restrict__ BT,
    unsigned short* As, unsigned short* Bs,
    int m0, int n0, int t, f4_t acc[4][2])
{
    int lane = t & 63, wid = t >> 6;
    int l16 = lane & 15, g4 = lane >> 4;
    int wr = wid >> 1, wc = wid & 1;

    // per-lane global addresses for staging
    const unsigned short* Ap = A  + (size_t)(m0 + 32 * wid + (lane >> 3)) * HID + (lane & 7) * 8;
    const unsigned short* Bp = BT + (size_t)(n0 + 16 * wid + (lane >> 3)) * HID + (lane & 7) * 8;
    unsigned short* AsW = As + (32 * wid) * 64;   // wave-uniform LDS bases
    unsigned short* BsW = Bs + (16 * wid) * 64;

    for (int k0 = 0; k0 < HID; k0 += 64) {
        __syncthreads();   // prior compute done reading LDS
        #pragma unroll
        for (int c = 0; c < 4; ++c)
            __builtin_amdgcn_global_load_lds((glb_u32*)(Ap + (size_t)c * 8 * HID + k0),
                                             (lds_u32*)(AsW + c * 8 * 64), 16, 0, 0);
        #pragma unroll
        for (int c = 0; c < 2; ++c)
            __builtin_amdgcn_global_load_lds((glb_u32*)(Bp + (size_t)c * 8 * HID + k0),
                                             (lds_u32*)(BsW + c * 8 * 64), 16, 0, 0);
        __syncthreads();   // compiler drains vmcnt(0) here

        #pragma unroll
        for (int kc = 0; kc < 2; ++kc) {
            bf8_t af[4], bfr[2];
            #pragma unroll
            for (int mi = 0; mi < 4; ++mi)
                af[mi] = *(const bf8_t*)&As[(wr * 64 + mi * 16 + l16) * 64 + 32 * kc + 8 * g4];
            #pragma unroll
            for (int ni = 0; ni < 2; ++ni)
                bfr[ni] = *(const bf8_t*)&Bs[(wc * 32 + ni * 16 + l16) * 64 + 32 * kc + 8 * g4];
            #pragma unroll
            for (int mi = 0; mi < 4; ++mi)
                #pragma unroll
                for (int ni = 0; ni < 2; ++ni)
                    acc[mi][ni] = __builtin_amdgcn_mfma_f32_16x16x32_bf16(af[mi], bfr[ni], acc[mi][ni], 0, 0, 0);
        }
    }
}

// K1: QKV projection with RoPE epilogue
__global__ __launch_bounds__(256) void qkv_mfma_kernel(
    const unsigned short* __restrict__ A, const unsigned short* __restrict__ BT,
    const float* __restrict__ cosT, const float* __restrict__ sinT,
    unsigned short* __restrict__ Q, unsigned short* __restrict__ Ko,
    unsigned short* __restrict__ Vo)
{
    __shared__ unsigned short As[128 * 64];
    __shared__ unsigned short Bs[64 * 64];
    int n0 = blockIdx.x * 64, m0 = blockIdx.y * 128;
    int t = threadIdx.x;
    int lane = t & 63, wid = t >> 6;
    int l16 = lane & 15, g4 = lane >> 4;
    int wr = wid >> 1, wc = wid & 1;

    f4_t acc[4][2];
    #pragma unroll
    for (int mi = 0; mi < 4; ++mi)
        #pragma unroll
        for (int ni = 0; ni < 2; ++ni) acc[mi][ni] = (f4_t){0.f, 0.f, 0.f, 0.f};

    gemm_core(A, BT, As, Bs, m0, n0, t, acc);

    #pragma unroll
    for (int ni = 0; ni < 2; ++ni) {
        int n = n0 + wc * 32 + ni * 16 + l16;
        int d = n & 63;
        int odd = n & 1;
        #pragma unroll
        for (int mi = 0; mi < 4; ++mi) {
            #pragma unroll
            for (int r = 0; r < 4; ++r) {
                float x = acc[mi][ni][r];
                float xp = __shfl_xor(x, 1);
                int s = m0 + wr * 64 + mi * 16 + g4 * 4 + r;
                float val;
                if (n < QCOLS + KVCOLS) {
                    float cv = cosT[s * HD + d], sv = sinT[s * HD + d];
                    val = odd ? x * cv + xp * sv : x * cv - xp * sv;
                } else val = x;
                unsigned short ob = f2bf(val);
                if (n < QCOLS)                   Q[(size_t)s * QCOLS + n] = ob;
                else if (n < QCOLS + KVCOLS)     Ko[(size_t)s * KVCOLS + n - QCOLS] = ob;
                else                             Vo[(size_t)s * KVCOLS + n - QCOLS - KVCOLS] = ob;
            }
        }
    }
}

// K3: output projection (fp32 out)
__global__ __launch_bounds__(256) void out_mfma_kernel(
    const unsigned short* __restrict__ A, const unsigned short* __restrict__ BT,
    float* __restrict__ C)
{
    __shared__ unsigned short As[128 * 64];
    __shared__ unsigned short Bs[64 * 64];
    int n0 = blockIdx.x * 64, m0 = blockIdx.y * 128;
    int t = threadIdx.x;
    int lane = t & 63, wid = t >> 6;
    int l16 = lane & 15, g4 = lane >> 4;
    int wr = wid >> 1, wc = wid & 1;

    f4_t acc[4][2];
    #pragma unroll
    for (int mi = 0; mi < 4; ++mi)
        #pragma unroll
        for (int ni = 0; ni < 2; ++ni) acc[mi][ni] = (f4_t){0.f, 0.f, 0.f, 0.f};

    gemm_core(A, BT, As, Bs, m0, n0, t, acc);

    #pragma unroll
    for (int ni = 0; ni < 2; ++ni) {
        int n = n0 + wc * 32 + ni * 16 + l16;
        #pragma unroll
        for (int mi = 0; mi < 4; ++mi) {
            #pragma unroll
            for (int r = 0; r < 4; ++r) {
                int s = m0 + wr * 64 + mi * 16 + g4 * 4 + r;
                C[(size_t)s * HID + n] = acc[mi][ni][r];
            }
        }
    }
}

// ===========================================================================
// K2: causal flash attention, paired q-tiles for uniform work.
// Block = (pair p, head h): q-tiles qtA=p, qtB=31-p. Every block: 33 tile-iters.
// One K/V staging serves both q-tiles (2x MFMA per barrier pair).
// ===========================================================================
__device__ __forceinline__ void attn_tile_step(
    int kv0, int qw, bool diag, int l16, int g4,
    const unsigned short* Ks, const unsigned short* Vt, unsigned short* PsW,
    const bf8_t qa[2], f4_t o[4], float m_r[4], float l_r[4])
{
    f4_t s[4];
    #pragma unroll
    for (int n = 0; n < 4; ++n) s[n] = (f4_t){0.f, 0.f, 0.f, 0.f};
    #pragma unroll
    for (int kc = 0; kc < 2; ++kc) {
        #pragma unroll
        for (int n = 0; n < 4; ++n) {
            bf8_t kb = *(const bf8_t*)&Ks[(n * 16 + l16) * LDK + 32 * kc + 8 * g4];
            s[n] = __builtin_amdgcn_mfma_f32_16x16x32_bf16(qa[kc], kb, s[n], 0, 0, 0);
        }
    }
    #pragma unroll
    for (int r = 0; r < 4; ++r) {
        int qg = qw + g4 * 4 + r;
        float v0[4];
        float mx = -1e30f;
        #pragma unroll
        for (int n = 0; n < 4; ++n) {
            float x = s[n][r] * 0.125f;
            if (diag) { int kc_ = kv0 + n * 16 + l16; if (kc_ > qg) x = -1e30f; }
            v0[n] = x;
            mx = fmaxf(mx, x);
        }
        mx = fmaxf(mx, __shfl_xor(mx, 1, 16));
        mx = fmaxf(mx, __shfl_xor(mx, 2, 16));
        mx = fmaxf(mx, __shfl_xor(mx, 4, 16));
        mx = fmaxf(mx, __shfl_xor(mx, 8, 16));
        float mnew = fmaxf(m_r[r], mx);
        float alpha = __expf(m_r[r] - mnew);
        float rs = 0.f;
        #pragma unroll
        for (int n = 0; n < 4; ++n) {
            float p = __expf(v0[n] - mnew);
            rs += p;
            PsW[(g4 * 4 + r) * LDP + n * 16 + l16] = f2bf(p);
        }
        rs += __shfl_xor(rs, 1, 16);
        rs += __shfl_xor(rs, 2, 16);
        rs += __shfl_xor(rs, 4, 16);
        rs += __shfl_xor(rs, 8, 16);
        l_r[r] = l_r[r] * alpha + rs;
        m_r[r] = mnew;
        #pragma unroll
        for (int n = 0; n < 4; ++n) o[n][r] *= alpha;
    }
    #pragma unroll
    for (int kc = 0; kc < 2; ++kc) {
        bf8_t pa = *(const bf8_t*)&PsW[l16 * LDP + 32 * kc + 8 * g4];
        #pragma unroll
        for (int n = 0; n < 4; ++n) {
            bf8_t vb = *(const bf8_t*)&Vt[(n * 16 + l16) * LDV + 32 * kc + 8 * g4];
            o[n] = __builtin_amdgcn_mfma_f32_16x16x32_bf16(pa, vb, o[n], 0, 0, 0);
        }
    }
}

__global__ __launch_bounds__(256) void attn_mfma_kernel(
    const unsigned short* __restrict__ Q, const unsigned short* __restrict__ K,
    const unsigned short* __restrict__ V, unsigned short* __restrict__ O)
{
    __shared__ unsigned short Ks[64 * LDK];
    __shared__ unsigned short Vt[64 * LDV];   // transposed: Vt[d][kv]
    __shared__ unsigned short Ps[64 * LDP];   // per-wave 16-row regions

    int pr = blockIdx.x;            // 0..15
    int h  = blockIdx.y;
    int qtA = pr, qtB = 31 - pr;    // paired q-tiles: work = (qtA+1)+(qtB+1) = 33
    int kvh = h >> 2;
    int t = threadIdx.x;
    int wid = t >> 6, lane = t & 63;
    int l16 = lane & 15, g4 = lane >> 4;
    int qwA = qtA * 64 + wid * 16;
    int qwB = qtB * 64 + wid * 16;
    unsigned short* PsW = &Ps[wid * 16 * LDP];

    bf8_t qaA[2], qaB[2];
    qaA[0] = *(const bf8_t*)&Q[(size_t)(qwA + l16) * QCOLS + h * HD + 8 * g4];
    qaA[1] = *(const bf8_t*)&Q[(size_t)(qwA + l16) * QCOLS + h * HD + 32 + 8 * g4];
    qaB[0] = *(const bf8_t*)&Q[(size_t)(qwB + l16) * QCOLS + h * HD + 8 * g4];
    qaB[1] = *(const bf8_t*)&Q[(size_t)(qwB + l16) * QCOLS + h * HD + 32 + 8 * g4];

    f4_t oA[4], oB[4];
    float mA[4], mB[4], lA[4], lB[4];
    #pragma unroll
    for (int n = 0; n < 4; ++n) {
        oA[n] = (f4_t){0.f, 0.f, 0.f, 0.f};
        oB[n] = (f4_t){0.f, 0.f, 0.f, 0.f};
        mA[n] = -1e30f; mB[n] = -1e30f; lA[n] = 0.f; lB[n] = 0.f;
    }

    int ntiles = qtB + 1;
    for (int kt = 0; kt < ntiles; ++kt) {
        int kv0 = kt * 64;
        __syncthreads();
        #pragma unroll
        for (int i = 0; i < 2; ++i) {
            int c = t + i * 256;
            int row = c >> 3, col16 = c & 7;
            size_t gb = (size_t)(kv0 + row) * KVCOLS + kvh * HD + col16 * 8;
            bf8_t k8 = *(const bf8_t*)&K[gb];
            *(bf8_t*)&Ks[row * LDK + col16 * 8] = k8;
            bf8_t v8 = *(const bf8_t*)&V[gb];
            #pragma unroll
            for (int j = 0; j < 8; ++j)
                Vt[(col16 * 8 + j) * LDV + row] = (unsigned short)v8[j];
        }
        __syncthreads();

        // q-tile B is active for every kt; A only while kt <= qtA
        attn_tile_step(kv0, qwB, kt == qtB, l16, g4, Ks, Vt, PsW, qaB, oB, mB, lB);
        if (kt <= qtA)
            attn_tile_step(kv0, qwA, kt == qtA, l16, g4, Ks, Vt, PsW, qaA, oA, mA, lA);
    }

    #pragma unroll
    for (int r = 0; r < 4; ++r) {
        float invA = 1.0f / lA[r];
        float invB = 1.0f / lB[r];
        int qgA = qwA + g4 * 4 + r;
        int qgB = qwB + g4 * 4 + r;
        #pragma unroll
        for (int n = 0; n < 4; ++n) {
            O[(size_t)qgA * QCOLS + h * HD + n * 16 + l16] = f2bf(oA[n][r] * invA);
            O[(size_t)qgB * QCOLS + h * HD + n * 16 + l16] = f2bf(oB[n][r] * invB);
        }
    }
}

// ---------------------------------------------------------------------------
extern "C" void kernel_launch(void* const* d_in, const int* in_sizes, int n_in,
                              void* d_out, int out_size, void* d_ws, size_t ws_size,
                              hipStream_t stream) {
    const float* X  = (const float*)d_in[0];
    // d_in[1] = attention_mask: causal by construction; applied analytically
    const float* Wq = (const float*)d_in[2];
    const float* Wk = (const float*)d_in[3];
    const float* Wv = (const float*)d_in[4];
    const float* Wo = (const float*)d_in[5];
    float* out = (float*)d_out;

    float* ws   = (float*)d_ws;
    float* cosT = ws;                                     // 2048*64 f32
    float* sinT = cosT + SEQ*HD;                          // 2048*64 f32
    unsigned short* Xb  = (unsigned short*)(sinT + SEQ*HD);   // 2048*2048 bf16
    unsigned short* WT  = Xb + (size_t)SEQ*HID;               // 3072*2048 bf16
    unsigned short* WoT = WT + (size_t)3072*HID;              // 2048*2048 bf16
    unsigned short* Qb  = WoT + (size_t)HID*HID;              // 2048*2048
    unsigned short* Kb  = Qb + (size_t)SEQ*QCOLS;             // 2048*512
    unsigned short* Vb  = Kb + (size_t)SEQ*KVCOLS;            // 2048*512
    unsigned short* attnb = Vb + (size_t)SEQ*KVCOLS;          // 2048*2048

    rope_table_kernel<<<SEQ*HD/256, 256, 0, stream>>>(cosT, sinT);
    convert_x_kernel<<<SEQ*HID/4/256, 256, 0, stream>>>(X, Xb);
    transpose_w_kernel<<<dim3(QCOLS/32,  HID/32), 256, 0, stream>>>(Wq, QCOLS,  WT, 0);
    transpose_w_kernel<<<dim3(KVCOLS/32, HID/32), 256, 0, stream>>>(Wk, KVCOLS, WT, QCOLS);
    transpose_w_kernel<<<dim3(KVCOLS/32, HID/32), 256, 0, stream>>>(Wv, KVCOLS, WT, QCOLS + KVCOLS);
    transpose_w_kernel<<<dim3(HID/32,    HID/32), 256, 0, stream>>>(Wo, HID,    WoT, 0);

    dim3 g1(3072/64, SEQ/128);
    qkv_mfma_kernel<<<g1, 256, 0, stream>>>(Xb, WT, cosT, sinT, Qb, Kb, Vb);
    dim3 g2(16, NH);
    attn_mfma_kernel<<<g2, 256, 0, stream>>>(Qb, Kb, Vb, attnb);
    dim3 g3(HID/64, SEQ/128);
    out_mfma_kernel<<<g3, 256, 0, stream>>>(attnb, WoT, out);
}

// Round 6
// 362.415 us; speedup vs baseline: 5.1211x; 1.0150x over previous
//
#include <hip/hip_runtime.h>
#include <math.h>

#define SEQ     2048
#define HID     2048
#define NH      32
#define NKV     8
#define HD      64
#define QCOLS   (NH*HD)          // 2048
#define KVCOLS  (NKV*HD)         // 512

// attention LDS strides (bf16 elements)
#define LDK 72   // Ks[64][72]
#define LDV 76   // Vt[64][76]
#define LDP 72   // Ps per-wave [16][72] x4

#define CHROWS (SEQ*NH)          // rows per chunk in partial buffers (2048*32)

typedef __attribute__((ext_vector_type(8))) short bf8_t;   // 8 bf16 (4 VGPRs)
typedef __attribute__((ext_vector_type(4))) float f4_t;    // C/D frag

typedef __attribute__((address_space(1))) const unsigned int glb_u32;
typedef __attribute__((address_space(3))) unsigned int lds_u32;

__device__ inline unsigned short f2bf(float f) {
    union { float f; unsigned int u; } a; a.f = f;
    unsigned int u = a.u;
    u += 0x7fffu + ((u >> 16) & 1u);   // round-to-nearest-even (finite inputs)
    return (unsigned short)(u >> 16);
}

// ---------------------------------------------------------------------------
// K0: RoPE cos/sin tables.
// ---------------------------------------------------------------------------
__global__ void rope_table_kernel(float* __restrict__ cosT, float* __restrict__ sinT) {
    int i = blockIdx.x * blockDim.x + threadIdx.x;   // 0 .. SEQ*HD-1
    int srow = i >> 6;
    int d = i & 63;
    float inv = powf(500000.0f, -(float)(d & 31) / 32.0f);
    float a = (float)srow * inv;
    cosT[i] = cosf(a);
    sinT[i] = sinf(a);
}

// ---------------------------------------------------------------------------
// K0b: X fp32 -> bf16
// ---------------------------------------------------------------------------
__global__ void convert_x_kernel(const float* __restrict__ X, unsigned short* __restrict__ Xb) {
    int i = blockIdx.x * blockDim.x + threadIdx.x;
    float4 v = *(const float4*)&X[(size_t)i * 4];
    ushort4 o;
    o.x = f2bf(v.x); o.y = f2bf(v.y); o.z = f2bf(v.z); o.w = f2bf(v.w);
    *(ushort4*)&Xb[(size_t)i * 4] = o;
}

// ---------------------------------------------------------------------------
// K0c: all weight transposes in one kernel.
// Output row R in [0,5120): [0,2048)=Wq->WT, [2048,2560)=Wk->WT,
// [2560,3072)=Wv->WT, [3072,5120)=Wo->WoT (row R-3072).
// ---------------------------------------------------------------------------
__global__ __launch_bounds__(256) void transpose_all_kernel(
    const float* __restrict__ Wq, const float* __restrict__ Wk,
    const float* __restrict__ Wv, const float* __restrict__ Wo,
    unsigned short* __restrict__ WT, unsigned short* __restrict__ WoT)
{
    __shared__ float tile[32][33];
    int R0 = blockIdx.x * 32;       // output row base (n of source)
    int k0 = blockIdx.y * 32;
    const float* W; int N; int n0; unsigned short* dst; int drow;
    if (R0 < 2048)      { W = Wq; N = 2048; n0 = R0;        dst = WT;  drow = R0; }
    else if (R0 < 2560) { W = Wk; N = 512;  n0 = R0 - 2048; dst = WT;  drow = R0; }
    else if (R0 < 3072) { W = Wv; N = 512;  n0 = R0 - 2560; dst = WT;  drow = R0; }
    else                { W = Wo; N = 2048; n0 = R0 - 3072; dst = WoT; drow = R0 - 3072; }

    int t = threadIdx.x;
    int tx = t & 31, ty = t >> 5;
    #pragma unroll
    for (int i = 0; i < 4; ++i) {
        int k = ty + i * 8;
        tile[k][tx] = W[(size_t)(k0 + k) * N + n0 + tx];
    }
    __syncthreads();
    #pragma unroll
    for (int i = 0; i < 4; ++i) {
        int n = ty + i * 8;
        WT[0]; // no-op to keep symmetry
        dst[(size_t)(drow + n) * HID + k0 + tx] = f2bf(tile[tx][n]);
    }
}

// ===========================================================================
// GEMM: 128x128 tile (m97 structure), BK=64, global_load_lds staging,
// linear LDS [128][64]. 4 waves 2x2, wave = 64x64 = 4x4 frags 16x16x32.
// ===========================================================================
__device__ __forceinline__ void gemm_core128(
    const unsigned short* __restrict__ A, const unsigned short* __restrict__ BT,
    unsigned short* As, unsigned short* Bs,
    int m0, int n0, int t, f4_t acc[4][4])
{
    int lane = t & 63, wid = t >> 6;
    int l16 = lane & 15, g4 = lane >> 4;
    int wr = wid >> 1, wc = wid & 1;

    // staging: thread loads 16B; rows t>>3 (0..31) + 32c; cols (t&7)*8
    const unsigned short* Ap = A  + (size_t)(m0 + (t >> 3)) * HID + (t & 7) * 8;
    const unsigned short* Bp = BT + (size_t)(n0 + (t >> 3)) * HID + (t & 7) * 8;
    // wave-uniform LDS byte base: wave w covers rows w*8..w*8+7 per issue
    unsigned short* AsW = As + wid * 512;   // 8 rows * 64 el
    unsigned short* BsW = Bs + wid * 512;

    for (int k0 = 0; k0 < HID; k0 += 64) {
        __syncthreads();   // prior compute done reading LDS
        #pragma unroll
        for (int c = 0; c < 4; ++c)
            __builtin_amdgcn_global_load_lds((glb_u32*)(Ap + (size_t)(32 * c) * HID + k0),
                                             (lds_u32*)(AsW + c * 2048), 16, 0, 0);
        #pragma unroll
        for (int c = 0; c < 4; ++c)
            __builtin_amdgcn_global_load_lds((glb_u32*)(Bp + (size_t)(32 * c) * HID + k0),
                                             (lds_u32*)(BsW + c * 2048), 16, 0, 0);
        __syncthreads();   // compiler drains vmcnt(0) here

        #pragma unroll
        for (int kc = 0; kc < 2; ++kc) {
            bf8_t af[4], bfr[4];
            #pragma unroll
            for (int mi = 0; mi < 4; ++mi)
                af[mi] = *(const bf8_t*)&As[(wr * 64 + mi * 16 + l16) * 64 + 32 * kc + 8 * g4];
            #pragma unroll
            for (int ni = 0; ni < 4; ++ni)
                bfr[ni] = *(const bf8_t*)&Bs[(wc * 64 + ni * 16 + l16) * 64 + 32 * kc + 8 * g4];
            #pragma unroll
            for (int mi = 0; mi < 4; ++mi)
                #pragma unroll
                for (int ni = 0; ni < 4; ++ni)
                    acc[mi][ni] = __builtin_amdgcn_mfma_f32_16x16x32_bf16(af[mi], bfr[ni], acc[mi][ni], 0, 0, 0);
        }
    }
}

// K1: QKV projection with RoPE epilogue
__global__ __launch_bounds__(256) void qkv_mfma_kernel(
    const unsigned short* __restrict__ A, const unsigned short* __restrict__ BT,
    const float* __restrict__ cosT, const float* __restrict__ sinT,
    unsigned short* __restrict__ Q, unsigned short* __restrict__ Ko,
    unsigned short* __restrict__ Vo)
{
    __shared__ unsigned short As[128 * 64];
    __shared__ unsigned short Bs[128 * 64];
    int n0 = blockIdx.x * 128, m0 = blockIdx.y * 128;
    int t = threadIdx.x;
    int lane = t & 63, wid = t >> 6;
    int l16 = lane & 15, g4 = lane >> 4;
    int wr = wid >> 1, wc = wid & 1;

    f4_t acc[4][4];
    #pragma unroll
    for (int mi = 0; mi < 4; ++mi)
        #pragma unroll
        for (int ni = 0; ni < 4; ++ni) acc[mi][ni] = (f4_t){0.f, 0.f, 0.f, 0.f};

    gemm_core128(A, BT, As, Bs, m0, n0, t, acc);

    #pragma unroll
    for (int ni = 0; ni < 4; ++ni) {
        int n = n0 + wc * 64 + ni * 16 + l16;
        int d = n & 63;
        int odd = n & 1;
        #pragma unroll
        for (int mi = 0; mi < 4; ++mi) {
            #pragma unroll
            for (int r = 0; r < 4; ++r) {
                float x = acc[mi][ni][r];
                float xp = __shfl_xor(x, 1);
                int s = m0 + wr * 64 + mi * 16 + g4 * 4 + r;
                float val;
                if (n < QCOLS + KVCOLS) {
                    float cv = cosT[s * HD + d], sv = sinT[s * HD + d];
                    val = odd ? x * cv + xp * sv : x * cv - xp * sv;
                } else val = x;
                unsigned short ob = f2bf(val);
                if (n < QCOLS)                   Q[(size_t)s * QCOLS + n] = ob;
                else if (n < QCOLS + KVCOLS)     Ko[(size_t)s * KVCOLS + n - QCOLS] = ob;
                else                             Vo[(size_t)s * KVCOLS + n - QCOLS - KVCOLS] = ob;
            }
        }
    }
}

// K3: output projection (fp32 out)
__global__ __launch_bounds__(256) void out_mfma_kernel(
    const unsigned short* __restrict__ A, const unsigned short* __restrict__ BT,
    float* __restrict__ C)
{
    __shared__ unsigned short As[128 * 64];
    __shared__ unsigned short Bs[128 * 64];
    int n0 = blockIdx.x * 128, m0 = blockIdx.y * 128;
    int t = threadIdx.x;
    int lane = t & 63, wid = t >> 6;
    int l16 = lane & 15, g4 = lane >> 4;
    int wr = wid >> 1, wc = wid & 1;

    f4_t acc[4][4];
    #pragma unroll
    for (int mi = 0; mi < 4; ++mi)
        #pragma unroll
        for (int ni = 0; ni < 4; ++ni) acc[mi][ni] = (f4_t){0.f, 0.f, 0.f, 0.f};

    gemm_core128(A, BT, As, Bs, m0, n0, t, acc);

    #pragma unroll
    for (int ni = 0; ni < 4; ++ni) {
        int n = n0 + wc * 64 + ni * 16 + l16;
        #pragma unroll
        for (int mi = 0; mi < 4; ++mi) {
            #pragma unroll
            for (int r = 0; r < 4; ++r) {
                int s = m0 + wr * 64 + mi * 16 + g4 * 4 + r;
                C[(size_t)s * HID + n] = acc[mi][ni][r];
            }
        }
    }
}

// ===========================================================================
// K2: causal flash attention, paired q-tiles + split-KV (2 chunks by parity).
// Block (pr, h, c): q-tiles qtA=pr, qtB=31-pr; kv tiles kt = c, c+2, ...
// Writes unnormalized partials (O, m, l) to ws; combine kernel merges.
// ===========================================================================
__device__ __forceinline__ void attn_tile_step(
    int kv0, int qw, bool diag, int l16, int g4,
    const unsigned short* Ks, const unsigned short* Vt, unsigned short* PsW,
    const bf8_t qa[2], f4_t o[4], float m_r[4], float l_r[4])
{
    f4_t s[4];
    #pragma unroll
    for (int n = 0; n < 4; ++n) s[n] = (f4_t){0.f, 0.f, 0.f, 0.f};
    #pragma unroll
    for (int kc = 0; kc < 2; ++kc) {
        #pragma unroll
        for (int n = 0; n < 4; ++n) {
            bf8_t kb = *(const bf8_t*)&Ks[(n * 16 + l16) * LDK + 32 * kc + 8 * g4];
            s[n] = __builtin_amdgcn_mfma_f32_16x16x32_bf16(qa[kc], kb, s[n], 0, 0, 0);
        }
    }
    #pragma unroll
    for (int r = 0; r < 4; ++r) {
        int qg = qw + g4 * 4 + r;
        float v0[4];
        float mx = -1e30f;
        #pragma unroll
        for (int n = 0; n < 4; ++n) {
            float x = s[n][r] * 0.125f;
            if (diag) { int kc_ = kv0 + n * 16 + l16; if (kc_ > qg) x = -1e30f; }
            v0[n] = x;
            mx = fmaxf(mx, x);
        }
        mx = fmaxf(mx, __shfl_xor(mx, 1, 16));
        mx = fmaxf(mx, __shfl_xor(mx, 2, 16));
        mx = fmaxf(mx, __shfl_xor(mx, 4, 16));
        mx = fmaxf(mx, __shfl_xor(mx, 8, 16));
        float mnew = fmaxf(m_r[r], mx);
        float alpha = __expf(m_r[r] - mnew);
        float rs = 0.f;
        #pragma unroll
        for (int n = 0; n < 4; ++n) {
            float p = __expf(v0[n] - mnew);
            rs += p;
            PsW[(g4 * 4 + r) * LDP + n * 16 + l16] = f2bf(p);
        }
        rs += __shfl_xor(rs, 1, 16);
        rs += __shfl_xor(rs, 2, 16);
        rs += __shfl_xor(rs, 4, 16);
        rs += __shfl_xor(rs, 8, 16);
        l_r[r] = l_r[r] * alpha + rs;
        m_r[r] = mnew;
        #pragma unroll
        for (int n = 0; n < 4; ++n) o[n][r] *= alpha;
    }
    #pragma unroll
    for (int kc = 0; kc < 2; ++kc) {
        bf8_t pa = *(const bf8_t*)&PsW[l16 * LDP + 32 * kc + 8 * g4];
        #pragma unroll
        for (int n = 0; n < 4; ++n) {
            bf8_t vb = *(const bf8_t*)&Vt[(n * 16 + l16) * LDV + 32 * kc + 8 * g4];
            o[n] = __builtin_amdgcn_mfma_f32_16x16x32_bf16(pa, vb, o[n], 0, 0, 0);
        }
    }
}

__device__ __forceinline__ void write_partial(
    float* __restrict__ Op, float* __restrict__ mlb, int chunk, int h,
    int qw, int l16, int g4, const f4_t o[4], const float m_r[4], const float l_r[4])
{
    #pragma unroll
    for (int r = 0; r < 4; ++r) {
        int qg = qw + g4 * 4 + r;
        size_t base = (size_t)chunk * CHROWS + (size_t)qg * NH + h;
        #pragma unroll
        for (int n = 0; n < 4; ++n)
            Op[base * HD + n * 16 + l16] = o[n][r];
        if (l16 == 0) {
            mlb[base * 2 + 0] = m_r[r];
            mlb[base * 2 + 1] = l_r[r];
        }
    }
}

__global__ __launch_bounds__(256) void attn_mfma_kernel(
    const unsigned short* __restrict__ Q, const unsigned short* __restrict__ K,
    const unsigned short* __restrict__ V,
    float* __restrict__ Op, float* __restrict__ mlb)
{
    __shared__ unsigned short Ks[64 * LDK];
    __shared__ unsigned short Vt[64 * LDV];   // transposed: Vt[d][kv]
    __shared__ unsigned short Ps[64 * LDP];   // per-wave 16-row regions

    int pr = blockIdx.x;            // 0..15
    int h  = blockIdx.y;
    int ck = blockIdx.z;            // kv parity chunk 0/1
    int qtA = pr, qtB = 31 - pr;
    int kvh = h >> 2;
    int t = threadIdx.x;
    int wid = t >> 6, lane = t & 63;
    int l16 = lane & 15, g4 = lane >> 4;
    int qwA = qtA * 64 + wid * 16;
    int qwB = qtB * 64 + wid * 16;
    unsigned short* PsW = &Ps[wid * 16 * LDP];

    bf8_t qaA[2], qaB[2];
    qaA[0] = *(const bf8_t*)&Q[(size_t)(qwA + l16) * QCOLS + h * HD + 8 * g4];
    qaA[1] = *(const bf8_t*)&Q[(size_t)(qwA + l16) * QCOLS + h * HD + 32 + 8 * g4];
    qaB[0] = *(const bf8_t*)&Q[(size_t)(qwB + l16) * QCOLS + h * HD + 8 * g4];
    qaB[1] = *(const bf8_t*)&Q[(size_t)(qwB + l16) * QCOLS + h * HD + 32 + 8 * g4];

    f4_t oA[4], oB[4];
    float mA[4], mB[4], lA[4], lB[4];
    #pragma unroll
    for (int n = 0; n < 4; ++n) {
        oA[n] = (f4_t){0.f, 0.f, 0.f, 0.f};
        oB[n] = (f4_t){0.f, 0.f, 0.f, 0.f};
        mA[n] = -1e30f; mB[n] = -1e30f; lA[n] = 0.f; lB[n] = 0.f;
    }

    for (int kt = ck; kt <= qtB; kt += 2) {
        int kv0 = kt * 64;
        __syncthreads();
        #pragma unroll
        for (int i = 0; i < 2; ++i) {
            int c = t + i * 256;
            int row = c >> 3, col16 = c & 7;
            size_t gb = (size_t)(kv0 + row) * KVCOLS + kvh * HD + col16 * 8;
            bf8_t k8 = *(const bf8_t*)&K[gb];
            *(bf8_t*)&Ks[row * LDK + col16 * 8] = k8;
            bf8_t v8 = *(const bf8_t*)&V[gb];
            #pragma unroll
            for (int j = 0; j < 8; ++j)
                Vt[(col16 * 8 + j) * LDV + row] = (unsigned short)v8[j];
        }
        __syncthreads();

        attn_tile_step(kv0, qwB, kt == qtB, l16, g4, Ks, Vt, PsW, qaB, oB, mB, lB);
        if (kt <= qtA)
            attn_tile_step(kv0, qwA, kt == qtA, l16, g4, Ks, Vt, PsW, qaA, oA, mA, lA);
    }

    write_partial(Op, mlb, ck, h, qwA, l16, g4, oA, mA, lA);
    write_partial(Op, mlb, ck, h, qwB, l16, g4, oB, mB, lB);
}

// ---------------------------------------------------------------------------
// K2b: combine the two kv-chunks -> attnb (bf16 [s][h*64+d])
// ---------------------------------------------------------------------------
__global__ __launch_bounds__(256) void attn_combine_kernel(
    const float* __restrict__ Op, const float* __restrict__ mlb,
    unsigned short* __restrict__ attnb)
{
    int tid = blockIdx.x * 256 + threadIdx.x;   // 0 .. SEQ*NH*16
    int d4 = (tid & 15) * 4;
    int rh = tid >> 4;                           // s*NH + h
    size_t b0 = (size_t)rh;
    size_t b1 = (size_t)CHROWS + rh;
    float m0 = mlb[b0 * 2 + 0], l0 = mlb[b0 * 2 + 1];
    float m1 = mlb[b1 * 2 + 0], l1 = mlb[b1 * 2 + 1];
    float M = fmaxf(m0, m1);
    float w0 = __expf(m0 - M), w1 = __expf(m1 - M);
    float inv = 1.0f / (w0 * l0 + w1 * l1);
    float4 o0 = *(const float4*)&Op[b0 * HD + d4];
    float4 o1 = *(const float4*)&Op[b1 * HD + d4];
    ushort4 ov;
    ov.x = f2bf((w0 * o0.x + w1 * o1.x) * inv);
    ov.y = f2bf((w0 * o0.y + w1 * o1.y) * inv);
    ov.z = f2bf((w0 * o0.z + w1 * o1.z) * inv);
    ov.w = f2bf((w0 * o0.w + w1 * o1.w) * inv);
    // rh = s*32 + h ; output col = h*64 + d4
    *(ushort4*)&attnb[(size_t)rh * HD + d4] = ov;   // [s][h][d] == [s][h*64+d]
}

// ---------------------------------------------------------------------------
extern "C" void kernel_launch(void* const* d_in, const int* in_sizes, int n_in,
                              void* d_out, int out_size, void* d_ws, size_t ws_size,
                              hipStream_t stream) {
    const float* X  = (const float*)d_in[0];
    // d_in[1] = attention_mask: causal by construction; applied analytically
    const float* Wq = (const float*)d_in[2];
    const float* Wk = (const float*)d_in[3];
    const float* Wv = (const float*)d_in[4];
    const float* Wo = (const float*)d_in[5];
    float* out = (float*)d_out;

    float* ws   = (float*)d_ws;
    float* cosT = ws;                                     // 2048*64 f32
    float* sinT = cosT + SEQ*HD;                          // 2048*64 f32
    unsigned short* Xb  = (unsigned short*)(sinT + SEQ*HD);   // 2048*2048 bf16
    unsigned short* WT  = Xb + (size_t)SEQ*HID;               // 3072*2048 bf16
    unsigned short* WoT = WT + (size_t)3072*HID;              // 2048*2048 bf16
    unsigned short* Qb  = WoT + (size_t)HID*HID;              // 2048*2048
    unsigned short* Kb  = Qb + (size_t)SEQ*QCOLS;             // 2048*512
    unsigned short* Vb  = Kb + (size_t)SEQ*KVCOLS;            // 2048*512
    unsigned short* attnb = Vb + (size_t)SEQ*KVCOLS;          // 2048*2048
    float* Op  = (float*)(attnb + (size_t)SEQ*QCOLS);         // 2*2048*32*64 f32
    float* mlb = Op + (size_t)2*CHROWS*HD;                    // 2*2048*32*2 f32

    rope_table_kernel<<<SEQ*HD/256, 256, 0, stream>>>(cosT, sinT);
    convert_x_kernel<<<SEQ*HID/4/256, 256, 0, stream>>>(X, Xb);
    transpose_all_kernel<<<dim3(5120/32, HID/32), 256, 0, stream>>>(Wq, Wk, Wv, Wo, WT, WoT);

    dim3 g1(3072/128, SEQ/128);
    qkv_mfma_kernel<<<g1, 256, 0, stream>>>(Xb, WT, cosT, sinT, Qb, Kb, Vb);
    dim3 g2(16, NH, 2);
    attn_mfma_kernel<<<g2, 256, 0, stream>>>(Qb, Kb, Vb, Op, mlb);
    attn_combine_kernel<<<SEQ*NH*16/256, 256, 0, stream>>>(Op, mlb, attnb);
    dim3 g3(HID/128, SEQ/128);
    out_mfma_kernel<<<g3, 256, 0, stream>>>(attnb, WoT, out);
}

// Round 8
// 298.803 us; speedup vs baseline: 6.2113x; 1.2129x over previous
//
#include <hip/hip_runtime.h>
#include <math.h>

#define SEQ     2048
#define HID     2048
#define NH      32
#define NKV     8
#define HD      64
#define QCOLS   (NH*HD)          // 2048
#define KVCOLS  (NKV*HD)         // 512

#define LDP2 66   // P LDS row stride (bf16 el): 33 dwords -> spread banks

typedef __attribute__((ext_vector_type(8))) short bf8_t;   // 8 bf16 (4 VGPRs)
typedef __attribute__((ext_vector_type(4))) float f4_t;    // C/D frag

typedef __attribute__((address_space(1))) const unsigned int glb_u32;
typedef __attribute__((address_space(3))) unsigned int lds_u32;

__device__ inline unsigned short f2bf(float f) {
    union { float f; unsigned int u; } a; a.f = f;
    unsigned int u = a.u;
    u += 0x7fffu + ((u >> 16) & 1u);   // round-to-nearest-even (finite inputs)
    return (unsigned short)(u >> 16);
}
__device__ inline float bf2f(unsigned short b) {
    union { unsigned int u; float f; } a; a.u = ((unsigned int)b) << 16;
    return a.f;
}

// ---------------------------------------------------------------------------
// K0: RoPE cos/sin tables.
// ---------------------------------------------------------------------------
__global__ void rope_table_kernel(float* __restrict__ cosT, float* __restrict__ sinT) {
    int i = blockIdx.x * blockDim.x + threadIdx.x;   // 0 .. SEQ*HD-1
    int srow = i >> 6;
    int d = i & 63;
    float inv = powf(500000.0f, -(float)(d & 31) / 32.0f);
    float a = (float)srow * inv;
    cosT[i] = cosf(a);
    sinT[i] = sinf(a);
}

// ---------------------------------------------------------------------------
// K0b: X fp32 -> bf16
// ---------------------------------------------------------------------------
__global__ void convert_x_kernel(const float* __restrict__ X, unsigned short* __restrict__ Xb) {
    int i = blockIdx.x * blockDim.x + threadIdx.x;
    float4 v = *(const float4*)&X[(size_t)i * 4];
    ushort4 o;
    o.x = f2bf(v.x); o.y = f2bf(v.y); o.z = f2bf(v.z); o.w = f2bf(v.w);
    *(ushort4*)&Xb[(size_t)i * 4] = o;
}

// ---------------------------------------------------------------------------
// K0c: all weight transposes in one kernel (fp32 [K][N] -> bf16 [n][k]).
// ---------------------------------------------------------------------------
__global__ __launch_bounds__(256) void transpose_all_kernel(
    const float* __restrict__ Wq, const float* __restrict__ Wk,
    const float* __restrict__ Wv, const float* __restrict__ Wo,
    unsigned short* __restrict__ WT, unsigned short* __restrict__ WoT)
{
    __shared__ float tile[32][33];
    int R0 = blockIdx.x * 32;
    int k0 = blockIdx.y * 32;
    const float* W; int N; int n0; unsigned short* dst; int drow;
    if (R0 < 2048)      { W = Wq; N = 2048; n0 = R0;        dst = WT;  drow = R0; }
    else if (R0 < 2560) { W = Wk; N = 512;  n0 = R0 - 2048; dst = WT;  drow = R0; }
    else if (R0 < 3072) { W = Wv; N = 512;  n0 = R0 - 2560; dst = WT;  drow = R0; }
    else                { W = Wo; N = 2048; n0 = R0 - 3072; dst = WoT; drow = R0 - 3072; }

    int t = threadIdx.x;
    int tx = t & 31, ty = t >> 5;
    #pragma unroll
    for (int i = 0; i < 4; ++i) {
        int k = ty + i * 8;
        tile[k][tx] = W[(size_t)(k0 + k) * N + n0 + tx];
    }
    __syncthreads();
    #pragma unroll
    for (int i = 0; i < 4; ++i) {
        int n = ty + i * 8;
        dst[(size_t)(drow + n) * HID + k0 + tx] = f2bf(tile[tx][n]);
    }
}

// ===========================================================================
// GEMM core: 128x128 tile, BK=64, global_load_lds staging, linear LDS.
// ===========================================================================
__device__ __forceinline__ void gemm_core128(
    const unsigned short* __restrict__ A, const unsigned short* __restrict__ BT,
    unsigned short* As, unsigned short* Bs,
    int m0, int n0, int t, f4_t acc[4][4])
{
    int lane = t & 63, wid = t >> 6;
    int l16 = lane & 15, g4 = lane >> 4;
    int wr = wid >> 1, wc = wid & 1;

    const unsigned short* Ap = A  + (size_t)(m0 + (t >> 3)) * HID + (t & 7) * 8;
    const unsigned short* Bp = BT + (size_t)(n0 + (t >> 3)) * HID + (t & 7) * 8;
    unsigned short* AsW = As + wid * 512;
    unsigned short* BsW = Bs + wid * 512;

    for (int k0 = 0; k0 < HID; k0 += 64) {
        __syncthreads();
        #pragma unroll
        for (int c = 0; c < 4; ++c)
            __builtin_amdgcn_global_load_lds((glb_u32*)(Ap + (size_t)(32 * c) * HID + k0),
                                             (lds_u32*)(AsW + c * 2048), 16, 0, 0);
        #pragma unroll
        for (int c = 0; c < 4; ++c)
            __builtin_amdgcn_global_load_lds((glb_u32*)(Bp + (size_t)(32 * c) * HID + k0),
                                             (lds_u32*)(BsW + c * 2048), 16, 0, 0);
        __syncthreads();

        #pragma unroll
        for (int kc = 0; kc < 2; ++kc) {
            bf8_t af[4], bfr[4];
            #pragma unroll
            for (int mi = 0; mi < 4; ++mi)
                af[mi] = *(const bf8_t*)&As[(wr * 64 + mi * 16 + l16) * 64 + 32 * kc + 8 * g4];
            #pragma unroll
            for (int ni = 0; ni < 4; ++ni)
                bfr[ni] = *(const bf8_t*)&Bs[(wc * 64 + ni * 16 + l16) * 64 + 32 * kc + 8 * g4];
            #pragma unroll
            for (int mi = 0; mi < 4; ++mi)
                #pragma unroll
                for (int ni = 0; ni < 4; ++ni)
                    acc[mi][ni] = __builtin_amdgcn_mfma_f32_16x16x32_bf16(af[mi], bfr[ni], acc[mi][ni], 0, 0, 0);
        }
    }
}

// K1: QKV projection with RoPE epilogue; Q gets softmax scale folded in.
__global__ __launch_bounds__(256) void qkv_mfma_kernel(
    const unsigned short* __restrict__ A, const unsigned short* __restrict__ BT,
    const float* __restrict__ cosT, const float* __restrict__ sinT,
    unsigned short* __restrict__ Q, unsigned short* __restrict__ Ko,
    unsigned short* __restrict__ Vo)
{
    __shared__ unsigned short As[128 * 64];
    __shared__ unsigned short Bs[128 * 64];
    int n0 = blockIdx.x * 128, m0 = blockIdx.y * 128;
    int t = threadIdx.x;
    int lane = t & 63, wid = t >> 6;
    int l16 = lane & 15, g4 = lane >> 4;
    int wr = wid >> 1, wc = wid & 1;

    f4_t acc[4][4];
    #pragma unroll
    for (int mi = 0; mi < 4; ++mi)
        #pragma unroll
        for (int ni = 0; ni < 4; ++ni) acc[mi][ni] = (f4_t){0.f, 0.f, 0.f, 0.f};

    gemm_core128(A, BT, As, Bs, m0, n0, t, acc);

    #pragma unroll
    for (int ni = 0; ni < 4; ++ni) {
        int n = n0 + wc * 64 + ni * 16 + l16;
        int d = n & 63;
        int odd = n & 1;
        #pragma unroll
        for (int mi = 0; mi < 4; ++mi) {
            #pragma unroll
            for (int r = 0; r < 4; ++r) {
                float x = acc[mi][ni][r];
                float xp = __shfl_xor(x, 1);
                int s = m0 + wr * 64 + mi * 16 + g4 * 4 + r;
                float val;
                if (n < QCOLS + KVCOLS) {
                    float cv = cosT[s * HD + d], sv = sinT[s * HD + d];
                    val = odd ? x * cv + xp * sv : x * cv - xp * sv;
                } else val = x;
                if (n < QCOLS) val *= 0.125f;   // fold 1/sqrt(64) into Q
                unsigned short ob = f2bf(val);
                if (n < QCOLS)                   Q[(size_t)s * QCOLS + n] = ob;
                else if (n < QCOLS + KVCOLS)     Ko[(size_t)s * KVCOLS + n - QCOLS] = ob;
                else                             Vo[(size_t)s * KVCOLS + n - QCOLS - KVCOLS] = ob;
            }
        }
    }
}

// K3: output projection (fp32 out)
__global__ __launch_bounds__(256) void out_mfma_kernel(
    const unsigned short* __restrict__ A, const unsigned short* __restrict__ BT,
    float* __restrict__ C)
{
    __shared__ unsigned short As[128 * 64];
    __shared__ unsigned short Bs[128 * 64];
    int n0 = blockIdx.x * 128, m0 = blockIdx.y * 128;
    int t = threadIdx.x;
    int lane = t & 63, wid = t >> 6;
    int l16 = lane & 15, g4 = lane >> 4;
    int wr = wid >> 1, wc = wid & 1;

    f4_t acc[4][4];
    #pragma unroll
    for (int mi = 0; mi < 4; ++mi)
        #pragma unroll
        for (int ni = 0; ni < 4; ++ni) acc[mi][ni] = (f4_t){0.f, 0.f, 0.f, 0.f};

    gemm_core128(A, BT, As, Bs, m0, n0, t, acc);

    #pragma unroll
    for (int ni = 0; ni < 4; ++ni) {
        int n = n0 + wc * 64 + ni * 16 + l16;
        #pragma unroll
        for (int mi = 0; mi < 4; ++mi) {
            #pragma unroll
            for (int r = 0; r < 4; ++r) {
                int s = m0 + wr * 64 + mi * 16 + g4 * 4 + r;
                C[(size_t)s * HID + n] = acc[mi][ni][r];
            }
        }
    }
}

// ---------------------------------------------------------------------------
// K1b: V -> V^T global ([s][kvh*64+d] -> [kvh][d][s])
// ---------------------------------------------------------------------------
__global__ __launch_bounds__(256) void transpose_v_kernel(
    const unsigned short* __restrict__ Vb, unsigned short* __restrict__ Vtg)
{
    __shared__ unsigned short tile[64][72];
    int s0 = blockIdx.x * 64;
    int kvh = blockIdx.y;
    int t = threadIdx.x;
    int r = t >> 3, c = t & 7;
    #pragma unroll
    for (int i = 0; i < 2; ++i) {
        int row = r + i * 32;
        *(bf8_t*)&tile[row][c * 8] =
            *(const bf8_t*)&Vb[(size_t)(s0 + row) * KVCOLS + kvh * HD + c * 8];
    }
    __syncthreads();
    int d = t >> 2, sc = (t & 3) * 16;
    unsigned short ob[16];
    #pragma unroll
    for (int j = 0; j < 16; ++j) ob[j] = tile[sc + j][d];
    *(bf8_t*)&Vtg[(size_t)(kvh * HD + d) * SEQ + s0 + sc]     = *(bf8_t*)&ob[0];
    *(bf8_t*)&Vtg[(size_t)(kvh * HD + d) * SEQ + s0 + sc + 8] = *(bf8_t*)&ob[8];
}

// ===========================================================================
// K2: causal flash attention — barrier-free, swapped QK^T, global K/V frags.
// Block (pr, h, ck): 4 waves; q-blocks A=pr*128, B=(15-pr)*128 (wave: 32 q).
// S^T = mfma(K, Q): lane l16 = q, regs hold 16 kv -> in-lane softmax.
// O^T = mfma(V^T, P^T): q stays in-lane; only P goes through LDS.
// kv-tiles split by parity (ck); partials (bf16 O^T, f32 m/l) to ws.
// ===========================================================================
__global__ __launch_bounds__(256, 2) void attn_mfma_kernel(
    const unsigned short* __restrict__ Q, const unsigned short* __restrict__ K,
    const unsigned short* __restrict__ Vt,
    unsigned short* __restrict__ Opart, float* __restrict__ mlpart)
{
    __shared__ unsigned short Ps[4][32 * LDP2];
    int pr = blockIdx.x;            // 0..7
    int h  = blockIdx.y;
    int ck = blockIdx.z;            // kv parity chunk
    int kvh = h >> 2;
    int t = threadIdx.x;
    int w = t >> 6, lane = t & 63, l16 = lane & 15, g4 = lane >> 4;

    int qb[2];   qb[0] = pr * 128 + w * 32;  qb[1] = (15 - pr) * 128 + w * 32;
    int ktmax[2]; ktmax[0] = 2 * pr + 1;     ktmax[1] = 2 * (15 - pr) + 1;

    const unsigned short* Kb_ = K + kvh * HD;
    const unsigned short* Vb_ = Vt + (size_t)kvh * HD * SEQ;
    unsigned short* PsW = &Ps[w][0];

    bf8_t qa[2][2][2];
    #pragma unroll
    for (int b = 0; b < 2; ++b)
        #pragma unroll
        for (int ns = 0; ns < 2; ++ns)
            #pragma unroll
            for (int kc = 0; kc < 2; ++kc)
                qa[b][ns][kc] = *(const bf8_t*)&Q[(size_t)(qb[b] + ns * 16 + l16) * QCOLS
                                                  + h * HD + kc * 32 + 8 * g4];

    f4_t o[2][2][4];
    float ms[2][2], ls[2][2];
    #pragma unroll
    for (int b = 0; b < 2; ++b)
        #pragma unroll
        for (int ns = 0; ns < 2; ++ns) {
            ms[b][ns] = -1e30f; ls[b][ns] = 0.f;
            #pragma unroll
            for (int mt = 0; mt < 4; ++mt) o[b][ns][mt] = (f4_t){0.f, 0.f, 0.f, 0.f};
        }

    for (int kt = ck; kt <= ktmax[1]; kt += 2) {
        int kv0 = kt * 64;
        #pragma unroll
        for (int b = 1; b >= 0; --b) {
            if (b == 0 && kt > ktmax[0]) continue;    // beyond A's causal range
            if (kv0 > qb[b] + 31) continue;           // wave fully masked

            // ---- S^T = K · Q ----
            f4_t s[2][4];
            #pragma unroll
            for (int ns = 0; ns < 2; ++ns)
                #pragma unroll
                for (int mt = 0; mt < 4; ++mt) s[ns][mt] = (f4_t){0.f, 0.f, 0.f, 0.f};
            #pragma unroll
            for (int kc = 0; kc < 2; ++kc) {
                bf8_t af[4];
                #pragma unroll
                for (int mt = 0; mt < 4; ++mt)
                    af[mt] = *(const bf8_t*)&Kb_[(size_t)(kv0 + mt * 16 + l16) * KVCOLS
                                                 + kc * 32 + 8 * g4];
                #pragma unroll
                for (int mt = 0; mt < 4; ++mt)
                    #pragma unroll
                    for (int ns = 0; ns < 2; ++ns)
                        s[ns][mt] = __builtin_amdgcn_mfma_f32_16x16x32_bf16(
                            af[mt], qa[b][ns][kc], s[ns][mt], 0, 0, 0);
            }

            // ---- in-lane online softmax (q = l16) ----
            #pragma unroll
            for (int ns = 0; ns < 2; ++ns) {
                int qg = qb[b] + ns * 16 + l16;
                float x[16];
                float mx = -1e30f;
                #pragma unroll
                for (int mt = 0; mt < 4; ++mt)
                    #pragma unroll
                    for (int r = 0; r < 4; ++r) {
                        float v = s[ns][mt][r];
                        int kv = kv0 + mt * 16 + 4 * g4 + r;
                        v = (kv <= qg) ? v : -1e30f;
                        x[mt * 4 + r] = v;
                        mx = fmaxf(mx, v);
                    }
                mx = fmaxf(mx, __shfl_xor(mx, 16));
                mx = fmaxf(mx, __shfl_xor(mx, 32));
                float mn = fmaxf(ms[b][ns], mx);
                float al = __expf(ms[b][ns] - mn);
                float rs = 0.f;
                unsigned int pw[8];
                #pragma unroll
                for (int mt = 0; mt < 4; ++mt)
                    #pragma unroll
                    for (int rp = 0; rp < 2; ++rp) {
                        float p0 = __expf(x[mt * 4 + rp * 2]     - mn);
                        float p1 = __expf(x[mt * 4 + rp * 2 + 1] - mn);
                        rs += p0 + p1;
                        pw[mt * 2 + rp] = (unsigned int)f2bf(p0) | ((unsigned int)f2bf(p1) << 16);
                    }
                rs += __shfl_xor(rs, 16);
                rs += __shfl_xor(rs, 32);
                ls[b][ns] = ls[b][ns] * al + rs;
                ms[b][ns] = mn;
                #pragma unroll
                for (int mt = 0; mt < 4; ++mt) o[b][ns][mt] *= al;
                unsigned int* prow = (unsigned int*)&PsW[(ns * 16 + l16) * LDP2];
                #pragma unroll
                for (int mt = 0; mt < 4; ++mt)
                    #pragma unroll
                    for (int rp = 0; rp < 2; ++rp)
                        prow[mt * 8 + g4 * 2 + rp] = pw[mt * 2 + rp];
            }

            // ---- O^T += V^T · P^T  (P wave-local; same-wave DS in-order) ----
            #pragma unroll
            for (int kc = 0; kc < 2; ++kc) {
                bf8_t pb[2];
                #pragma unroll
                for (int ns = 0; ns < 2; ++ns)
                    pb[ns] = *(const bf8_t*)&PsW[(ns * 16 + l16) * LDP2 + kc * 32 + 8 * g4];
                #pragma unroll
                for (int mt = 0; mt < 4; ++mt) {
                    bf8_t vf = *(const bf8_t*)&Vb_[(size_t)(mt * 16 + l16) * SEQ
                                                   + kv0 + kc * 32 + 8 * g4];
                    #pragma unroll
                    for (int ns = 0; ns < 2; ++ns)
                        o[b][ns][mt] = __builtin_amdgcn_mfma_f32_16x16x32_bf16(
                            vf, pb[ns], o[b][ns][mt], 0, 0, 0);
                }
            }
        }
    }

    // ---- write partials: Opart[ck][h][d][s] bf16, mlpart[ck][h][s]{m,l} ----
    #pragma unroll
    for (int b = 0; b < 2; ++b)
        #pragma unroll
        for (int ns = 0; ns < 2; ++ns) {
            int qg = qb[b] + ns * 16 + l16;
            if (g4 == 0) {
                float2 mlv; mlv.x = ms[b][ns]; mlv.y = ls[b][ns];
                *(float2*)&mlpart[((size_t)(ck * NH + h) * SEQ + qg) * 2] = mlv;
            }
            #pragma unroll
            for (int mt = 0; mt < 4; ++mt)
                #pragma unroll
                for (int r = 0; r < 4; ++r)
                    Opart[((size_t)(ck * NH + h) * HD + mt * 16 + 4 * g4 + r) * SEQ + qg]
                        = f2bf(o[b][ns][mt][r]);
        }
}

// ---------------------------------------------------------------------------
// K2b: combine chunks + transpose -> attnb[s][h*64+d] bf16
// ---------------------------------------------------------------------------
__global__ __launch_bounds__(256) void attn_combine_kernel(
    const unsigned short* __restrict__ Opart, const float* __restrict__ mlpart,
    unsigned short* __restrict__ attnb)
{
    __shared__ float comb[64][66];
    __shared__ float wbuf[3][64];
    int s0 = blockIdx.x * 64;
    int h  = blockIdx.y;
    int t = threadIdx.x;
    if (t < 64) {
        int s = s0 + t;
        float2 ml0 = *(const float2*)&mlpart[((size_t)(0 * NH + h) * SEQ + s) * 2];
        float2 ml1 = *(const float2*)&mlpart[((size_t)(1 * NH + h) * SEQ + s) * 2];
        float M = fmaxf(ml0.x, ml1.x);
        float w0 = __expf(ml0.x - M), w1 = __expf(ml1.x - M);
        wbuf[0][t] = w0;
        wbuf[1][t] = w1;
        wbuf[2][t] = 1.0f / (w0 * ml0.y + w1 * ml1.y);
    }
    __syncthreads();
    int d = t >> 2, sc = (t & 3) * 16;
    const unsigned short* p0 = &Opart[((size_t)(0 * NH + h) * HD + d) * SEQ + s0 + sc];
    const unsigned short* p1 = &Opart[((size_t)(1 * NH + h) * HD + d) * SEQ + s0 + sc];
    #pragma unroll
    for (int j8 = 0; j8 < 2; ++j8) {
        bf8_t a0 = *(const bf8_t*)(p0 + j8 * 8);
        bf8_t a1 = *(const bf8_t*)(p1 + j8 * 8);
        #pragma unroll
        for (int j = 0; j < 8; ++j) {
            int s = sc + j8 * 8 + j;
            float v0 = bf2f((unsigned short)a0[j]);
            float v1 = bf2f((unsigned short)a1[j]);
            comb[d][s] = (wbuf[0][s] * v0 + wbuf[1][s] * v1) * wbuf[2][s];
        }
    }
    __syncthreads();
    int s = t >> 2, dc = (t & 3) * 16;
    unsigned short ob[16];
    #pragma unroll
    for (int j = 0; j < 16; ++j) ob[j] = f2bf(comb[dc + j][s]);
    *(bf8_t*)&attnb[(size_t)(s0 + s) * QCOLS + h * HD + dc]     = *(bf8_t*)&ob[0];
    *(bf8_t*)&attnb[(size_t)(s0 + s) * QCOLS + h * HD + dc + 8] = *(bf8_t*)&ob[8];
}

// ---------------------------------------------------------------------------
extern "C" void kernel_launch(void* const* d_in, const int* in_sizes, int n_in,
                              void* d_out, int out_size, void* d_ws, size_t ws_size,
                              hipStream_t stream) {
    const float* X  = (const float*)d_in[0];
    // d_in[1] = attention_mask: causal by construction; applied analytically
    const float* Wq = (const float*)d_in[2];
    const float* Wk = (const float*)d_in[3];
    const float* Wv = (const float*)d_in[4];
    const float* Wo = (const float*)d_in[5];
    float* out = (float*)d_out;

    float* ws   = (float*)d_ws;
    float* cosT = ws;                                         // 2048*64 f32
    float* sinT = cosT + SEQ*HD;                              // 2048*64 f32
    unsigned short* Xb  = (unsigned short*)(sinT + SEQ*HD);   // 2048*2048 bf16
    unsigned short* WT  = Xb + (size_t)SEQ*HID;               // 3072*2048 bf16
    unsigned short* WoT = WT + (size_t)3072*HID;              // 2048*2048 bf16
    unsigned short* Qb  = WoT + (size_t)HID*HID;              // 2048*2048
    unsigned short* Kb  = Qb + (size_t)SEQ*QCOLS;             // 2048*512
    unsigned short* Vb  = Kb + (size_t)SEQ*KVCOLS;            // 2048*512
    unsigned short* Vtg = Vb + (size_t)SEQ*KVCOLS;            // 512*2048 (V^T)
    unsigned short* attnb = Vtg + (size_t)KVCOLS*SEQ;         // 2048*2048
    unsigned short* Opart = attnb + (size_t)SEQ*QCOLS;        // 2*32*64*2048 bf16
    float* mlpart = (float*)(Opart + (size_t)2*NH*HD*SEQ);    // 2*32*2048*2 f32

    rope_table_kernel<<<SEQ*HD/256, 256, 0, stream>>>(cosT, sinT);
    convert_x_kernel<<<SEQ*HID/4/256, 256, 0, stream>>>(X, Xb);
    transpose_all_kernel<<<dim3(5120/32, HID/32), 256, 0, stream>>>(Wq, Wk, Wv, Wo, WT, WoT);

    dim3 g1(3072/128, SEQ/128);
    qkv_mfma_kernel<<<g1, 256, 0, stream>>>(Xb, WT, cosT, sinT, Qb, Kb, Vb);
    transpose_v_kernel<<<dim3(SEQ/64, NKV), 256, 0, stream>>>(Vb, Vtg);

    dim3 g2(8, NH, 2);
    attn_mfma_kernel<<<g2, 256, 0, stream>>>(Qb, Kb, Vtg, Opart, mlpart);
    attn_combine_kernel<<<dim3(SEQ/64, NH), 256, 0, stream>>>(Opart, mlpart, attnb);

    dim3 g3(HID/128, SEQ/128);
    out_mfma_kernel<<<g3, 256, 0, stream>>>(attnb, WoT, out);
}